// Round 5
// baseline (195.928 us; speedup 1.0000x reference)
//
#include <hip/hip_runtime.h>
#include <hip/hip_bf16.h>

#define B_ 4
#define T_ 64
#define N_ 325
#define F_ 3
#define DH 16
#define DD 64
#define NH 4
#define BT_ 256                 // B*T
#define M_ 4096                 // BT*DH  (GEMM N-dim)
#define GK 32

// ---------------- K1: S = adj + 2*adj@adj  (325x325) — tiled GEMM ------------
__global__ __launch_bounds__(256) void k_support(const float* __restrict__ adj, float* __restrict__ S) {
    __shared__ float As[GK][68];
    __shared__ float Bs[GK][64];
    int m0 = blockIdx.x * 64, i0 = blockIdx.y * 64;
    int tid = threadIdx.x;
    int ti = tid & 15, tm = tid >> 4;
    float acc[4][4];
#pragma unroll
    for (int a = 0; a < 4; ++a)
#pragma unroll
        for (int q = 0; q < 4; ++q) acc[a][q] = 0.f;

    for (int k0 = 0; k0 < N_; k0 += GK) {
#pragma unroll
        for (int p = 0; p < 8; ++p) {
            int e = tid + p * 256;
            int j = e & 31, r = e >> 5;
            int row = i0 + r, col = k0 + j;
            As[j][r] = (row < N_ && col < N_) ? adj[row * N_ + col] : 0.f;
        }
#pragma unroll
        for (int p = 0; p < 8; ++p) {
            int e = tid + p * 256;
            int mm = e & 63, j = e >> 6;
            int col = k0 + j, m = m0 + mm;
            Bs[j & 31][mm] = 0.f;   // init below overwritten; keep simple
            Bs[j][mm] = (col < N_ && m < N_) ? adj[col * N_ + m] : 0.f;
        }
        __syncthreads();
#pragma unroll
        for (int j = 0; j < GK; ++j) {
            float a0 = As[j][ti * 4 + 0], a1 = As[j][ti * 4 + 1];
            float a2 = As[j][ti * 4 + 2], a3 = As[j][ti * 4 + 3];
            float b0 = Bs[j][tm * 4 + 0], b1 = Bs[j][tm * 4 + 1];
            float b2 = Bs[j][tm * 4 + 2], b3 = Bs[j][tm * 4 + 3];
            acc[0][0] += a0 * b0; acc[0][1] += a0 * b1; acc[0][2] += a0 * b2; acc[0][3] += a0 * b3;
            acc[1][0] += a1 * b0; acc[1][1] += a1 * b1; acc[1][2] += a1 * b2; acc[1][3] += a1 * b3;
            acc[2][0] += a2 * b0; acc[2][1] += a2 * b1; acc[2][2] += a2 * b2; acc[2][3] += a2 * b3;
            acc[3][0] += a3 * b0; acc[3][1] += a3 * b1; acc[3][2] += a3 * b2; acc[3][3] += a3 * b3;
        }
        __syncthreads();
    }
#pragma unroll
    for (int a = 0; a < 4; ++a) {
        int i = i0 + ti * 4 + a;
        if (i < N_) {
#pragma unroll
            for (int q = 0; q < 4; ++q) {
                int m = m0 + tm * 4 + q;
                if (m < N_) S[i * N_ + m] = adj[i * N_ + m] + 2.f * acc[a][q];
            }
        }
    }
}

// ---------------- K2: X2[n][bt][c] = relu(inputs @ w_lt^T + b_lt) ------------
__global__ void k_lintrans(const float* __restrict__ in,
                           const float* __restrict__ w,    // (16,3)
                           const float* __restrict__ bias, // (16)
                           float* __restrict__ X2) {
    int idx = blockIdx.x * 256 + threadIdx.x;   // over N*BT*16
    if (idx >= N_ * M_) return;
    int n = idx >> 12;
    int r = idx & 4095;
    int bt = r >> 4, c = r & 15;
    int tok = bt * N_ + n;
    float f0 = in[tok * 3 + 0];
    float f1 = in[tok * 3 + 1];
    float f2 = in[tok * 3 + 2];
    float a = bias[c] + f0 * w[c * 3 + 0] + f1 * w[c * 3 + 1] + f2 * w[c * 3 + 2];
    X2[idx] = fmaxf(a, 0.f);
}

// ---------------- K3: lfs2(325 x 4096) = S(325x325) @ X2(325x4096) -----------
__global__ __launch_bounds__(256) void k_gconv(const float* __restrict__ S,
                                               const float* __restrict__ X2,
                                               float* __restrict__ lfs2) {
    __shared__ float As[GK][68];
    __shared__ float Bs[GK][64];
    int m0 = blockIdx.x * 64;
    int i0 = blockIdx.y * 64;
    int tid = threadIdx.x;
    int ti = tid & 15, tm = tid >> 4;

    float acc[4][4];
#pragma unroll
    for (int a = 0; a < 4; ++a)
#pragma unroll
        for (int q = 0; q < 4; ++q) acc[a][q] = 0.f;

    for (int k0 = 0; k0 < N_; k0 += GK) {
#pragma unroll
        for (int p = 0; p < 8; ++p) {
            int e = tid + p * 256;
            int j = e & 31, r = e >> 5;
            int row = i0 + r, col = k0 + j;
            As[j][r] = (row < N_ && col < N_) ? S[row * N_ + col] : 0.f;
        }
#pragma unroll
        for (int p = 0; p < 8; ++p) {
            int e = tid + p * 256;
            int mm = e & 63, j = e >> 6;
            int col = k0 + j;
            Bs[j][mm] = (col < N_) ? X2[(size_t)col * M_ + m0 + mm] : 0.f;
        }
        __syncthreads();
#pragma unroll
        for (int j = 0; j < GK; ++j) {
            float a0 = As[j][ti * 4 + 0], a1 = As[j][ti * 4 + 1];
            float a2 = As[j][ti * 4 + 2], a3 = As[j][ti * 4 + 3];
            float b0 = Bs[j][tm * 4 + 0], b1 = Bs[j][tm * 4 + 1];
            float b2 = Bs[j][tm * 4 + 2], b3 = Bs[j][tm * 4 + 3];
            acc[0][0] += a0 * b0; acc[0][1] += a0 * b1; acc[0][2] += a0 * b2; acc[0][3] += a0 * b3;
            acc[1][0] += a1 * b0; acc[1][1] += a1 * b1; acc[1][2] += a1 * b2; acc[1][3] += a1 * b3;
            acc[2][0] += a2 * b0; acc[2][1] += a2 * b1; acc[2][2] += a2 * b2; acc[2][3] += a2 * b3;
            acc[3][0] += a3 * b0; acc[3][1] += a3 * b1; acc[3][2] += a3 * b2; acc[3][3] += a3 * b3;
        }
        __syncthreads();
    }
#pragma unroll
    for (int a = 0; a < 4; ++a) {
        int i = i0 + ti * 4 + a;
        if (i < N_) {
            float* dst = lfs2 + (size_t)i * M_ + m0 + tm * 4;
            dst[0] = acc[a][0]; dst[1] = acc[a][1]; dst[2] = acc[a][2]; dst[3] = acc[a][3];
        }
    }
}

// ---------------- K4: fused QKV + attention + concat + w_ls + residual -------
// one block per (b,n); 256 threads = 4 waves (wave = head, lane = query row).
// ypre written in [b][n][t][c] layout (contiguous per block).
#define KS4 68
__global__ __launch_bounds__(256) void k_attn(
    const float* __restrict__ lfs2, const float* __restrict__ X2,
    const float* __restrict__ wq, const float* __restrict__ bq,
    const float* __restrict__ wk, const float* __restrict__ bk,
    const float* __restrict__ wv, const float* __restrict__ bv,
    const float* __restrict__ wls, const float* __restrict__ bls,
    float* __restrict__ ypre) {
    __shared__ float Lf[T_][17];                    // 4.25 KB (2-way = free)
    __shared__ __align__(16) float Ks[T_][KS4];     // 17 KB, 16B-aligned rows (reused for R)
    __shared__ __align__(16) float Vs[T_][KS4];     // 17 KB
    __shared__ float Vp[4][DD];                     // V column partial sums
    __shared__ float Vcs[DD];                       // V column sums
    int b = blockIdx.x / N_, n = blockIdx.x % N_;
    int tid = threadIdx.x;
    const float* Lsrc = lfs2 + (size_t)n * M_ + b * (T_ * DH);   // 1024 contiguous

    for (int idx = tid; idx < T_ * DH; idx += 256)
        Lf[idx >> 4][idx & 15] = Lsrc[idx];
    __syncthreads();

    // K,V: thread owns column o = tid&63, rows t = tid>>6 step 4
    {
        int o = tid & 63;
        float wkc[DH], wvc[DH];
#pragma unroll
        for (int c = 0; c < DH; ++c) {
            wkc[c] = wk[c * DD + o];
            wvc[c] = wv[c * DD + o];
        }
        float bko = bk[o], bvo = bv[o], vsum = 0.f;
        for (int t = tid >> 6; t < T_; t += 4) {
            float ak = bko, av = bvo;
#pragma unroll
            for (int c = 0; c < DH; ++c) {
                float x = Lf[t][c];   // wave-uniform broadcast
                ak += x * wkc[c]; av += x * wvc[c];
            }
            Ks[t][o] = fmaxf(ak, 0.f);
            float vv = fmaxf(av, 0.f);
            Vs[t][o] = vv;
            vsum += vv;
        }
        Vp[tid >> 6][o] = vsum;
    }
    __syncthreads();
    if (tid < DD) Vcs[tid] = Vp[0][tid] + Vp[1][tid] + Vp[2][tid] + Vp[3][tid];
    __syncthreads();

    // attention
    {
        int h = tid >> 6;    // head
        int t = tid & 63;    // query row
        float q[DH];
#pragma unroll
        for (int c = 0; c < DH; ++c) {
            float a = bq[h * DH + c];                   // wave-uniform -> scalar
#pragma unroll
            for (int k = 0; k < DH; ++k)
                a += Lf[t][k] * wq[k * DD + h * DH + c];
            q[c] = fmaxf(a, 0.f);
        }
        float p[T_];
        float m = -1e30f;
#pragma unroll
        for (int s = 0; s < T_; ++s) {
            const float4* Kr = (const float4*)&Ks[s][h * DH];
            float4 k0 = Kr[0], k1 = Kr[1], k2 = Kr[2], k3 = Kr[3];
            float acc = q[0]*k0.x + q[1]*k0.y + q[2]*k0.z + q[3]*k0.w
                      + q[4]*k1.x + q[5]*k1.y + q[6]*k1.z + q[7]*k1.w
                      + q[8]*k2.x + q[9]*k2.y + q[10]*k2.z + q[11]*k2.w
                      + q[12]*k3.x + q[13]*k3.y + q[14]*k3.z + q[15]*k3.w;
            acc *= 0.25f;
            p[s] = acc;
            m = fmaxf(m, acc);
        }
        float sum = 0.f;
#pragma unroll
        for (int s = 0; s < T_; ++s) { float e = __expf(p[s] - m); p[s] = e; sum += e; }
        float inv = 1.f / sum;
        float r[DH];
#pragma unroll
        for (int c = 0; c < DH; ++c) r[c] = 0.f;
#pragma unroll
        for (int s = 0; s < T_; ++s) {
            float a = (s <= t) ? p[s] * inv - 1e-9f : 0.f;   // mask AFTER softmax; 1e-9 tail via Vcs
            const float4* Vr = (const float4*)&Vs[s][h * DH];
            float4 v0 = Vr[0], v1 = Vr[1], v2 = Vr[2], v3 = Vr[3];
            r[0] += a*v0.x; r[1] += a*v0.y; r[2] += a*v0.z; r[3] += a*v0.w;
            r[4] += a*v1.x; r[5] += a*v1.y; r[6] += a*v1.z; r[7] += a*v1.w;
            r[8] += a*v2.x; r[9] += a*v2.y; r[10] += a*v2.z; r[11] += a*v2.w;
            r[12] += a*v3.x; r[13] += a*v3.y; r[14] += a*v3.z; r[15] += a*v3.w;
        }
#pragma unroll
        for (int c = 0; c < DH; ++c) r[c] += 1e-9f * Vcs[h * DH + c];
        __syncthreads();           // all waves done reading Ks/Vs
        float4* Rr = (float4*)&Ks[t][h * DH];
        Rr[0] = make_float4(fmaxf(r[0],0.f),  fmaxf(r[1],0.f),  fmaxf(r[2],0.f),  fmaxf(r[3],0.f));
        Rr[1] = make_float4(fmaxf(r[4],0.f),  fmaxf(r[5],0.f),  fmaxf(r[6],0.f),  fmaxf(r[7],0.f));
        Rr[2] = make_float4(fmaxf(r[8],0.f),  fmaxf(r[9],0.f),  fmaxf(r[10],0.f), fmaxf(r[11],0.f));
        Rr[3] = make_float4(fmaxf(r[12],0.f), fmaxf(r[13],0.f), fmaxf(r[14],0.f), fmaxf(r[15],0.f));
    }
    __syncthreads();

    // output projection (64->16) + residual; ypre layout [b][n][t][c] contiguous
    {
        int oo = tid & 15;
        float wl[DD];
#pragma unroll
        for (int k = 0; k < DD; ++k) wl[k] = wls[oo * DD + k];
        float bo = bls[oo];
        const float* Xsrc = X2 + (size_t)n * M_ + b * (T_ * DH);
        float* Ydst = ypre + (size_t)b * 332800 + (size_t)n * (T_ * DH);
        for (int tt = tid >> 4; tt < T_; tt += 16) {
            float acc = bo;
            const float4* Rr = (const float4*)&Ks[tt][0];
#pragma unroll
            for (int k4 = 0; k4 < 16; ++k4) {
                float4 rv = Rr[k4];
                acc += wl[k4*4+0]*rv.x + wl[k4*4+1]*rv.y + wl[k4*4+2]*rv.z + wl[k4*4+3]*rv.w;
            }
            Ydst[tt * DH + oo] = Xsrc[tt * DH + oo] + fmaxf(acc, 0.f);
        }
    }
}

// ---------------- K5: per-batch partial sums (64 chunks per batch) -----------
__global__ __launch_bounds__(256) void k_lnpart(const float* __restrict__ y, float* __restrict__ part) {
    __shared__ float ssum[256], ssq[256];
    int b = blockIdx.x >> 6, chunk = blockIdx.x & 63;
    const float* yb = y + (size_t)b * 332800 + (size_t)chunk * 5200;
    float s = 0.f, q2 = 0.f;
    for (int i = threadIdx.x; i < 5200; i += 256) { float v = yb[i]; s += v; q2 += v * v; }
    ssum[threadIdx.x] = s; ssq[threadIdx.x] = q2;
    __syncthreads();
    for (int st = 128; st > 0; st >>= 1) {
        if (threadIdx.x < st) {
            ssum[threadIdx.x] += ssum[threadIdx.x + st];
            ssq[threadIdx.x] += ssq[threadIdx.x + st];
        }
        __syncthreads();
    }
    if (threadIdx.x == 0) { part[blockIdx.x * 2] = ssum[0]; part[blockIdx.x * 2 + 1] = ssq[0]; }
}

// ---------------- K6: stat finalize (folded) + normalize + gamma/beta --------
// y layout [b][n][t][c]; out layout [b][t][n][c]; gamma/beta (c,t,n)
__global__ __launch_bounds__(256) void k_lnapply(const float* __restrict__ y,
                                                 const float* __restrict__ part,
                                                 const float* __restrict__ gamma,
                                                 const float* __restrict__ beta,
                                                 float* __restrict__ out) {
    __shared__ float sred[2];
    int tid = threadIdx.x;
    int b = blockIdx.x / 1300;           // 1300 blocks per batch
    float s = 0.f, q = 0.f;
    if (tid < 64) { s = part[(b * 64 + tid) * 2]; q = part[(b * 64 + tid) * 2 + 1]; }
#pragma unroll
    for (int off = 32; off > 0; off >>= 1) { s += __shfl_down(s, off); q += __shfl_down(q, off); }
    if (tid == 0) {
        float mu = s / 332800.f;
        float var = q / 332800.f - mu * mu;
        sred[0] = mu; sred[1] = rsqrtf(var + 1e-5f);
    }
    __syncthreads();
    float mu = sred[0], rs = sred[1];
    int idx = blockIdx.x * 256 + tid;
    int r = idx - b * 332800;
    int n = r >> 10;
    int rr = r & 1023;
    int t = rr >> 4, c = rr & 15;
    int g = (c * T_ + t) * N_ + n;
    float v = (y[idx] - mu) * rs * gamma[g] + beta[g];
    out[(((size_t)(b * T_ + t) * N_) + n) * DH + c] = v;
}

extern "C" void kernel_launch(void* const* d_in, const int* in_sizes, int n_in,
                              void* d_out, int out_size, void* d_ws, size_t ws_size,
                              hipStream_t stream) {
    const float* in   = (const float*)d_in[0];
    const float* adj  = (const float*)d_in[1];
    const float* w_lt = (const float*)d_in[2];
    const float* b_lt = (const float*)d_in[3];
    const float* wq   = (const float*)d_in[4];
    const float* bq   = (const float*)d_in[5];
    const float* wk   = (const float*)d_in[6];
    const float* bk   = (const float*)d_in[7];
    const float* wv   = (const float*)d_in[8];
    const float* bv   = (const float*)d_in[9];
    const float* wls  = (const float*)d_in[10];
    const float* bls  = (const float*)d_in[11];
    const float* gam  = (const float*)d_in[12];
    const float* bet  = (const float*)d_in[13];
    float* out = (float*)d_out;

    float* ws = (float*)d_ws;
    float* S    = ws;                       // 105,625 -> pad 105,728
    float* X2   = S + 105728;               // 1,331,200  (layout n, bt, c)
    float* lfs2 = X2 + 1331200;             // 1,331,200  (layout n, bt, c)
    float* ypre = lfs2 + 1331200;           // 1,331,200  (layout b, n, t, c)
    float* part = ypre + 1331200;           // 512

    k_support<<<dim3(6, 6), 256, 0, stream>>>(adj, S);
    k_lintrans<<<(N_ * M_) / 256, 256, 0, stream>>>(in, w_lt, b_lt, X2);
    k_gconv<<<dim3(M_ / 64, (N_ + 63) / 64), 256, 0, stream>>>(S, X2, lfs2);
    k_attn<<<B_ * N_, 256, 0, stream>>>(lfs2, X2, wq, bq, wk, bk, wv, bv, wls, bls, ypre);
    k_lnpart<<<256, 256, 0, stream>>>(ypre, part);
    k_lnapply<<<(B_ * T_ * N_ * DH) / 256, 256, 0, stream>>>(ypre, part, gam, bet, out);
}

// Round 6
// 166.528 us; speedup vs baseline: 1.1765x; 1.1765x over previous
//
#include <hip/hip_runtime.h>
#include <hip/hip_bf16.h>

#define B_ 4
#define T_ 64
#define N_ 325
#define F_ 3
#define DH 16
#define DD 64
#define NH 4
#define BT_ 256                 // B*T
#define M_ 4096                 // BT*DH  (GEMM N-dim)
#define GK 32

// ---------------- K1: S = adj + 2*adj@adj  (325x325) ------------------------
// 32x32 tiles, 2x2 micro-tile, BK=64; 121 blocks for latency (tiny GEMM =>
// parallelism over reuse; the 64x64/36-block version was latency-starved).
#define SBM 32
#define SBK 64
__global__ __launch_bounds__(256) void k_support(const float* __restrict__ adj, float* __restrict__ S) {
    __shared__ float As[SBK][33];  // As[k][ii] = adj[(i0+ii)*N + k0+k]
    __shared__ float Bs[SBK][33];  // Bs[k][jj] = adj[(k0+k)*N + j0+jj]
    int j0 = blockIdx.x * SBM, i0 = blockIdx.y * SBM;
    int tid = threadIdx.x;
    int ti = tid & 15, tj = tid >> 4;
    float a00 = 0.f, a01 = 0.f, a10 = 0.f, a11 = 0.f;
    for (int k0 = 0; k0 < N_; k0 += SBK) {
#pragma unroll
        for (int p = 0; p < 8; ++p) {           // A: coalesced on k
            int e = tid + p * 256;
            int k = e & 63, ii = e >> 6;
            int row = i0 + ii, col = k0 + k;
            As[k][ii] = (row < N_ && col < N_) ? adj[row * N_ + col] : 0.f;
        }
#pragma unroll
        for (int p = 0; p < 8; ++p) {           // B: coalesced on j
            int e = tid + p * 256;
            int jj = e & 31, k = e >> 5;
            int row = k0 + k, col = j0 + jj;
            Bs[k][jj] = (row < N_ && col < N_) ? adj[row * N_ + col] : 0.f;
        }
        __syncthreads();
#pragma unroll
        for (int k = 0; k < SBK; ++k) {
            float x0 = As[k][ti * 2], x1 = As[k][ti * 2 + 1];
            float y0 = Bs[k][tj * 2], y1 = Bs[k][tj * 2 + 1];
            a00 += x0 * y0; a01 += x0 * y1; a10 += x1 * y0; a11 += x1 * y1;
        }
        __syncthreads();
    }
    int i = i0 + ti * 2, j = j0 + tj * 2;
    if (i < N_ && j < N_)         S[i * N_ + j]           = adj[i * N_ + j]           + 2.f * a00;
    if (i < N_ && j + 1 < N_)     S[i * N_ + j + 1]       = adj[i * N_ + j + 1]       + 2.f * a01;
    if (i + 1 < N_ && j < N_)     S[(i + 1) * N_ + j]     = adj[(i + 1) * N_ + j]     + 2.f * a10;
    if (i + 1 < N_ && j + 1 < N_) S[(i + 1) * N_ + j + 1] = adj[(i + 1) * N_ + j + 1] + 2.f * a11;
}

// ---------------- K2: X2[n][bt][c] = relu(inputs @ w_lt^T + b_lt) ------------
__global__ void k_lintrans(const float* __restrict__ in,
                           const float* __restrict__ w,    // (16,3)
                           const float* __restrict__ bias, // (16)
                           float* __restrict__ X2) {
    int idx = blockIdx.x * 256 + threadIdx.x;   // over N*BT*16
    if (idx >= N_ * M_) return;
    int n = idx >> 12;
    int r = idx & 4095;
    int bt = r >> 4, c = r & 15;
    int tok = bt * N_ + n;
    float f0 = in[tok * 3 + 0];
    float f1 = in[tok * 3 + 1];
    float f2 = in[tok * 3 + 2];
    float a = bias[c] + f0 * w[c * 3 + 0] + f1 * w[c * 3 + 1] + f2 * w[c * 3 + 2];
    X2[idx] = fmaxf(a, 0.f);
}

// ---------------- K3: lfs2(325 x 4096) = S(325x325) @ X2(325x4096) -----------
__global__ __launch_bounds__(256) void k_gconv(const float* __restrict__ S,
                                               const float* __restrict__ X2,
                                               float* __restrict__ lfs2) {
    __shared__ float As[GK][68];
    __shared__ float Bs[GK][64];
    int m0 = blockIdx.x * 64;
    int i0 = blockIdx.y * 64;
    int tid = threadIdx.x;
    int ti = tid & 15, tm = tid >> 4;

    float acc[4][4];
#pragma unroll
    for (int a = 0; a < 4; ++a)
#pragma unroll
        for (int q = 0; q < 4; ++q) acc[a][q] = 0.f;

    for (int k0 = 0; k0 < N_; k0 += GK) {
#pragma unroll
        for (int p = 0; p < 8; ++p) {
            int e = tid + p * 256;
            int j = e & 31, r = e >> 5;
            int row = i0 + r, col = k0 + j;
            As[j][r] = (row < N_ && col < N_) ? S[row * N_ + col] : 0.f;
        }
#pragma unroll
        for (int p = 0; p < 8; ++p) {
            int e = tid + p * 256;
            int mm = e & 63, j = e >> 6;
            int col = k0 + j;
            Bs[j][mm] = (col < N_) ? X2[(size_t)col * M_ + m0 + mm] : 0.f;
        }
        __syncthreads();
#pragma unroll
        for (int j = 0; j < GK; ++j) {
            float a0 = As[j][ti * 4 + 0], a1 = As[j][ti * 4 + 1];
            float a2 = As[j][ti * 4 + 2], a3 = As[j][ti * 4 + 3];
            float b0 = Bs[j][tm * 4 + 0], b1 = Bs[j][tm * 4 + 1];
            float b2 = Bs[j][tm * 4 + 2], b3 = Bs[j][tm * 4 + 3];
            acc[0][0] += a0 * b0; acc[0][1] += a0 * b1; acc[0][2] += a0 * b2; acc[0][3] += a0 * b3;
            acc[1][0] += a1 * b0; acc[1][1] += a1 * b1; acc[1][2] += a1 * b2; acc[1][3] += a1 * b3;
            acc[2][0] += a2 * b0; acc[2][1] += a2 * b1; acc[2][2] += a2 * b2; acc[2][3] += a2 * b3;
            acc[3][0] += a3 * b0; acc[3][1] += a3 * b1; acc[3][2] += a3 * b2; acc[3][3] += a3 * b3;
        }
        __syncthreads();
    }
#pragma unroll
    for (int a = 0; a < 4; ++a) {
        int i = i0 + ti * 4 + a;
        if (i < N_) {
            float* dst = lfs2 + (size_t)i * M_ + m0 + tm * 4;
            dst[0] = acc[a][0]; dst[1] = acc[a][1]; dst[2] = acc[a][2]; dst[3] = acc[a][3];
        }
    }
}

// ---------------- K4: fused QKV + attention + concat + w_ls + residual -------
// one block per (b,n); 256 threads = 4 waves (wave = head, lane = query row).
// ypre written in [b][n][t][c] layout (contiguous per block).
#define KS4 68
__global__ __launch_bounds__(256) void k_attn(
    const float* __restrict__ lfs2, const float* __restrict__ X2,
    const float* __restrict__ wq, const float* __restrict__ bq,
    const float* __restrict__ wk, const float* __restrict__ bk,
    const float* __restrict__ wv, const float* __restrict__ bv,
    const float* __restrict__ wls, const float* __restrict__ bls,
    float* __restrict__ ypre) {
    __shared__ float Lf[T_][17];                    // 4.25 KB (2-way = free)
    __shared__ __align__(16) float Ks[T_][KS4];     // 17 KB, 16B-aligned rows (reused for R)
    __shared__ __align__(16) float Vs[T_][KS4];     // 17 KB
    __shared__ float Vp[4][DD];                     // V column partial sums
    __shared__ float Vcs[DD];                       // V column sums
    int b = blockIdx.x / N_, n = blockIdx.x % N_;
    int tid = threadIdx.x;
    const float* Lsrc = lfs2 + (size_t)n * M_ + b * (T_ * DH);   // 1024 contiguous

    for (int idx = tid; idx < T_ * DH; idx += 256)
        Lf[idx >> 4][idx & 15] = Lsrc[idx];
    __syncthreads();

    // K,V: thread owns column o = tid&63, rows t = tid>>6 step 4
    {
        int o = tid & 63;
        float wkc[DH], wvc[DH];
#pragma unroll
        for (int c = 0; c < DH; ++c) {
            wkc[c] = wk[c * DD + o];
            wvc[c] = wv[c * DD + o];
        }
        float bko = bk[o], bvo = bv[o], vsum = 0.f;
        for (int t = tid >> 6; t < T_; t += 4) {
            float ak = bko, av = bvo;
#pragma unroll
            for (int c = 0; c < DH; ++c) {
                float x = Lf[t][c];   // wave-uniform broadcast
                ak += x * wkc[c]; av += x * wvc[c];
            }
            Ks[t][o] = fmaxf(ak, 0.f);
            float vv = fmaxf(av, 0.f);
            Vs[t][o] = vv;
            vsum += vv;
        }
        Vp[tid >> 6][o] = vsum;
    }
    __syncthreads();
    if (tid < DD) Vcs[tid] = Vp[0][tid] + Vp[1][tid] + Vp[2][tid] + Vp[3][tid];
    __syncthreads();

    // attention
    {
        int h = tid >> 6;    // head
        int t = tid & 63;    // query row
        float q[DH];
#pragma unroll
        for (int c = 0; c < DH; ++c) {
            float a = bq[h * DH + c];                   // wave-uniform -> scalar
#pragma unroll
            for (int k = 0; k < DH; ++k)
                a += Lf[t][k] * wq[k * DD + h * DH + c];
            q[c] = fmaxf(a, 0.f);
        }
        float p[T_];
        float m = -1e30f;
#pragma unroll
        for (int s = 0; s < T_; ++s) {
            const float4* Kr = (const float4*)&Ks[s][h * DH];
            float4 k0 = Kr[0], k1 = Kr[1], k2 = Kr[2], k3 = Kr[3];
            float acc = q[0]*k0.x + q[1]*k0.y + q[2]*k0.z + q[3]*k0.w
                      + q[4]*k1.x + q[5]*k1.y + q[6]*k1.z + q[7]*k1.w
                      + q[8]*k2.x + q[9]*k2.y + q[10]*k2.z + q[11]*k2.w
                      + q[12]*k3.x + q[13]*k3.y + q[14]*k3.z + q[15]*k3.w;
            acc *= 0.25f;
            p[s] = acc;
            m = fmaxf(m, acc);
        }
        float sum = 0.f;
#pragma unroll
        for (int s = 0; s < T_; ++s) { float e = __expf(p[s] - m); p[s] = e; sum += e; }
        float inv = 1.f / sum;
        float r[DH];
#pragma unroll
        for (int c = 0; c < DH; ++c) r[c] = 0.f;
#pragma unroll
        for (int s = 0; s < T_; ++s) {
            float a = (s <= t) ? p[s] * inv - 1e-9f : 0.f;   // mask AFTER softmax; 1e-9 tail via Vcs
            const float4* Vr = (const float4*)&Vs[s][h * DH];
            float4 v0 = Vr[0], v1 = Vr[1], v2 = Vr[2], v3 = Vr[3];
            r[0] += a*v0.x; r[1] += a*v0.y; r[2] += a*v0.z; r[3] += a*v0.w;
            r[4] += a*v1.x; r[5] += a*v1.y; r[6] += a*v1.z; r[7] += a*v1.w;
            r[8] += a*v2.x; r[9] += a*v2.y; r[10] += a*v2.z; r[11] += a*v2.w;
            r[12] += a*v3.x; r[13] += a*v3.y; r[14] += a*v3.z; r[15] += a*v3.w;
        }
#pragma unroll
        for (int c = 0; c < DH; ++c) r[c] += 1e-9f * Vcs[h * DH + c];
        __syncthreads();           // all waves done reading Ks/Vs
        float4* Rr = (float4*)&Ks[t][h * DH];
        Rr[0] = make_float4(fmaxf(r[0],0.f),  fmaxf(r[1],0.f),  fmaxf(r[2],0.f),  fmaxf(r[3],0.f));
        Rr[1] = make_float4(fmaxf(r[4],0.f),  fmaxf(r[5],0.f),  fmaxf(r[6],0.f),  fmaxf(r[7],0.f));
        Rr[2] = make_float4(fmaxf(r[8],0.f),  fmaxf(r[9],0.f),  fmaxf(r[10],0.f), fmaxf(r[11],0.f));
        Rr[3] = make_float4(fmaxf(r[12],0.f), fmaxf(r[13],0.f), fmaxf(r[14],0.f), fmaxf(r[15],0.f));
    }
    __syncthreads();

    // output projection (64->16) + residual; ypre layout [b][n][t][c] contiguous
    {
        int oo = tid & 15;
        float wl[DD];
#pragma unroll
        for (int k = 0; k < DD; ++k) wl[k] = wls[oo * DD + k];
        float bo = bls[oo];
        const float* Xsrc = X2 + (size_t)n * M_ + b * (T_ * DH);
        float* Ydst = ypre + (size_t)b * 332800 + (size_t)n * (T_ * DH);
        for (int tt = tid >> 4; tt < T_; tt += 16) {
            float acc = bo;
            const float4* Rr = (const float4*)&Ks[tt][0];
#pragma unroll
            for (int k4 = 0; k4 < 16; ++k4) {
                float4 rv = Rr[k4];
                acc += wl[k4*4+0]*rv.x + wl[k4*4+1]*rv.y + wl[k4*4+2]*rv.z + wl[k4*4+3]*rv.w;
            }
            Ydst[tt * DH + oo] = Xsrc[tt * DH + oo] + fmaxf(acc, 0.f);
        }
    }
}

// ---------------- K5: per-batch partial sums (64 chunks per batch) -----------
__global__ __launch_bounds__(256) void k_lnpart(const float* __restrict__ y, float* __restrict__ part) {
    __shared__ float ssum[256], ssq[256];
    int b = blockIdx.x >> 6, chunk = blockIdx.x & 63;
    const float* yb = y + (size_t)b * 332800 + (size_t)chunk * 5200;
    float s = 0.f, q2 = 0.f;
    for (int i = threadIdx.x; i < 5200; i += 256) { float v = yb[i]; s += v; q2 += v * v; }
    ssum[threadIdx.x] = s; ssq[threadIdx.x] = q2;
    __syncthreads();
    for (int st = 128; st > 0; st >>= 1) {
        if (threadIdx.x < st) {
            ssum[threadIdx.x] += ssum[threadIdx.x + st];
            ssq[threadIdx.x] += ssq[threadIdx.x + st];
        }
        __syncthreads();
    }
    if (threadIdx.x == 0) { part[blockIdx.x * 2] = ssum[0]; part[blockIdx.x * 2 + 1] = ssq[0]; }
}

// ---------------- K6: stat finalize (folded) + normalize + gamma/beta --------
// y layout [b][n][t][c]; out layout [b][t][n][c]; gamma/beta (c,t,n)
__global__ __launch_bounds__(256) void k_lnapply(const float* __restrict__ y,
                                                 const float* __restrict__ part,
                                                 const float* __restrict__ gamma,
                                                 const float* __restrict__ beta,
                                                 float* __restrict__ out) {
    __shared__ float sred[2];
    int tid = threadIdx.x;
    int b = blockIdx.x / 1300;           // 1300 blocks per batch
    float s = 0.f, q = 0.f;
    if (tid < 64) { s = part[(b * 64 + tid) * 2]; q = part[(b * 64 + tid) * 2 + 1]; }
#pragma unroll
    for (int off = 32; off > 0; off >>= 1) { s += __shfl_down(s, off); q += __shfl_down(q, off); }
    if (tid == 0) {
        float mu = s / 332800.f;
        float var = q / 332800.f - mu * mu;
        sred[0] = mu; sred[1] = rsqrtf(var + 1e-5f);
    }
    __syncthreads();
    float mu = sred[0], rs = sred[1];
    int idx = blockIdx.x * 256 + tid;
    int r = idx - b * 332800;
    int n = r >> 10;
    int rr = r & 1023;
    int t = rr >> 4, c = rr & 15;
    int g = (c * T_ + t) * N_ + n;
    float v = (y[idx] - mu) * rs * gamma[g] + beta[g];
    out[(((size_t)(b * T_ + t) * N_) + n) * DH + c] = v;
}

extern "C" void kernel_launch(void* const* d_in, const int* in_sizes, int n_in,
                              void* d_out, int out_size, void* d_ws, size_t ws_size,
                              hipStream_t stream) {
    const float* in   = (const float*)d_in[0];
    const float* adj  = (const float*)d_in[1];
    const float* w_lt = (const float*)d_in[2];
    const float* b_lt = (const float*)d_in[3];
    const float* wq   = (const float*)d_in[4];
    const float* bq   = (const float*)d_in[5];
    const float* wk   = (const float*)d_in[6];
    const float* bk   = (const float*)d_in[7];
    const float* wv   = (const float*)d_in[8];
    const float* bv   = (const float*)d_in[9];
    const float* wls  = (const float*)d_in[10];
    const float* bls  = (const float*)d_in[11];
    const float* gam  = (const float*)d_in[12];
    const float* bet  = (const float*)d_in[13];
    float* out = (float*)d_out;

    float* ws = (float*)d_ws;
    float* S    = ws;                       // 105,625 -> pad 105,728
    float* X2   = S + 105728;               // 1,331,200  (layout n, bt, c)
    float* lfs2 = X2 + 1331200;             // 1,331,200  (layout n, bt, c)
    float* ypre = lfs2 + 1331200;           // 1,331,200  (layout b, n, t, c)
    float* part = ypre + 1331200;           // 512

    k_support<<<dim3(11, 11), 256, 0, stream>>>(adj, S);
    k_lintrans<<<(N_ * M_) / 256, 256, 0, stream>>>(in, w_lt, b_lt, X2);
    k_gconv<<<dim3(M_ / 64, (N_ + 63) / 64), 256, 0, stream>>>(S, X2, lfs2);
    k_attn<<<B_ * N_, 256, 0, stream>>>(lfs2, X2, wq, bq, wk, bk, wv, bv, wls, bls, ypre);
    k_lnpart<<<256, 256, 0, stream>>>(ypre, part);
    k_lnapply<<<(B_ * T_ * N_ * DH) / 256, 256, 0, stream>>>(ypre, part, gam, bet, out);
}

// Round 7
// 163.061 us; speedup vs baseline: 1.2016x; 1.0213x over previous
//
#include <hip/hip_runtime.h>
#include <hip/hip_bf16.h>

#define B_ 4
#define T_ 64
#define N_ 325
#define F_ 3
#define DH 16
#define DD 64
#define NH 4
#define BT_ 256                 // B*T
#define M_ 4096                 // BT*DH  (GEMM N-dim)

// ---------------- K1: S = adj + 2*adj@adj  (325x325) ------------------------
// 32x32 tiles, 2x2 micro-tile, BK=64; 121 blocks (latency: parallelism > reuse)
#define SBM 32
#define SBK 64
__global__ __launch_bounds__(256) void k_support(const float* __restrict__ adj, float* __restrict__ S) {
    __shared__ float As[SBK][33];  // As[k][ii] = adj[(i0+ii)*N + k0+k]
    __shared__ float Bs[SBK][33];  // Bs[k][jj] = adj[(k0+k)*N + j0+jj]
    int j0 = blockIdx.x * SBM, i0 = blockIdx.y * SBM;
    int tid = threadIdx.x;
    int ti = tid & 15, tj = tid >> 4;
    float a00 = 0.f, a01 = 0.f, a10 = 0.f, a11 = 0.f;
    for (int k0 = 0; k0 < N_; k0 += SBK) {
#pragma unroll
        for (int p = 0; p < 8; ++p) {           // A: coalesced on k
            int e = tid + p * 256;
            int k = e & 63, ii = e >> 6;
            int row = i0 + ii, col = k0 + k;
            As[k][ii] = (row < N_ && col < N_) ? adj[row * N_ + col] : 0.f;
        }
#pragma unroll
        for (int p = 0; p < 8; ++p) {           // B: coalesced on j
            int e = tid + p * 256;
            int jj = e & 31, k = e >> 5;
            int row = k0 + k, col = j0 + jj;
            Bs[k][jj] = (row < N_ && col < N_) ? adj[row * N_ + col] : 0.f;
        }
        __syncthreads();
#pragma unroll
        for (int k = 0; k < SBK; ++k) {
            float x0 = As[k][ti * 2], x1 = As[k][ti * 2 + 1];
            float y0 = Bs[k][tj * 2], y1 = Bs[k][tj * 2 + 1];
            a00 += x0 * y0; a01 += x0 * y1; a10 += x1 * y0; a11 += x1 * y1;
        }
        __syncthreads();
    }
    int i = i0 + ti * 2, j = j0 + tj * 2;
    if (i < N_ && j < N_)         S[i * N_ + j]           = adj[i * N_ + j]           + 2.f * a00;
    if (i < N_ && j + 1 < N_)     S[i * N_ + j + 1]       = adj[i * N_ + j + 1]       + 2.f * a01;
    if (i + 1 < N_ && j < N_)     S[(i + 1) * N_ + j]     = adj[(i + 1) * N_ + j]     + 2.f * a10;
    if (i + 1 < N_ && j + 1 < N_) S[(i + 1) * N_ + j + 1] = adj[(i + 1) * N_ + j + 1] + 2.f * a11;
}

// ---------------- K2: X2[n][bt][c] = relu(inputs @ w_lt^T + b_lt) ------------
// 4 outputs/thread, float4 store
__global__ void k_lintrans(const float* __restrict__ in,
                           const float* __restrict__ w,    // (16,3)
                           const float* __restrict__ bias, // (16)
                           float* __restrict__ X2) {
    int idx4 = (blockIdx.x * 256 + threadIdx.x) * 4;   // over N*BT*16
    if (idx4 >= N_ * M_) return;
    int n = idx4 >> 12;
    int r = idx4 & 4095;
    int bt = r >> 4, c0 = r & 15;
    int tok = bt * N_ + n;
    float f0 = in[tok * 3 + 0];
    float f1 = in[tok * 3 + 1];
    float f2 = in[tok * 3 + 2];
    float4 o;
    o.x = fmaxf(bias[c0+0] + f0*w[(c0+0)*3+0] + f1*w[(c0+0)*3+1] + f2*w[(c0+0)*3+2], 0.f);
    o.y = fmaxf(bias[c0+1] + f0*w[(c0+1)*3+0] + f1*w[(c0+1)*3+1] + f2*w[(c0+1)*3+2], 0.f);
    o.z = fmaxf(bias[c0+2] + f0*w[(c0+2)*3+0] + f1*w[(c0+2)*3+1] + f2*w[(c0+2)*3+2], 0.f);
    o.w = fmaxf(bias[c0+3] + f0*w[(c0+3)*3+0] + f1*w[(c0+3)*3+1] + f2*w[(c0+3)*3+2], 0.f);
    *(float4*)&X2[idx4] = o;
}

// ---------------- K3: lfs2(325 x 4096) = S(325x325) @ X2(325x4096) -----------
// scalar-broadcast GEMM: S rows via SGPR (wave-uniform), X2 coalesced, no LDS.
// block = 8 S-rows x 256 m-cols; grid (16, 41) = 656 blocks.
#define GI 8
__global__ __launch_bounds__(256) void k_gconv(const float* __restrict__ S,
                                               const float* __restrict__ X2,
                                               float* __restrict__ lfs2) {
    int m = blockIdx.x * 256 + threadIdx.x;
    int i0 = blockIdx.y * GI;
    float acc[GI];
#pragma unroll
    for (int r = 0; r < GI; ++r) acc[r] = 0.f;
#pragma unroll 8
    for (int k = 0; k < N_; ++k) {
        float x = X2[(size_t)k * M_ + m];
#pragma unroll
        for (int r = 0; r < GI; ++r)
            acc[r] += S[(i0 + r) * N_ + k] * x;   // uniform addr -> s_load
    }
    int rows = N_ - i0; if (rows > GI) rows = GI;
    for (int r = 0; r < rows; ++r)
        lfs2[(size_t)(i0 + r) * M_ + m] = acc[r];
}

// ---------------- K4: fused QKV + attention + concat + w_ls + residual -------
// one block per (b,n); 256 threads = 4 waves (wave = head, lane = query row).
// ILP: all long accumulator chains split into independent partials.
#define KS4 68
__global__ __launch_bounds__(256) void k_attn(
    const float* __restrict__ lfs2, const float* __restrict__ X2,
    const float* __restrict__ wq, const float* __restrict__ bq,
    const float* __restrict__ wk, const float* __restrict__ bk,
    const float* __restrict__ wv, const float* __restrict__ bv,
    const float* __restrict__ wls, const float* __restrict__ bls,
    float* __restrict__ ypre) {
    __shared__ float Lf[T_][17];                    // 4.25 KB (2-way = free)
    __shared__ __align__(16) float Ks[T_][KS4];     // 17 KB (reused for R)
    __shared__ __align__(16) float Vs[T_][KS4];     // 17 KB
    __shared__ float Vp[4][DD];
    __shared__ float Vcs[DD];
    int b = blockIdx.x / N_, n = blockIdx.x % N_;
    int tid = threadIdx.x;
    const float* Lsrc = lfs2 + (size_t)n * M_ + b * (T_ * DH);   // 1024 contiguous

    for (int idx = tid; idx < T_ * DH; idx += 256)
        Lf[idx >> 4][idx & 15] = Lsrc[idx];
    __syncthreads();

    // K,V: thread owns column o = tid&63, rows t = tid>>6 step 4 (4 chains x 8)
    {
        int o = tid & 63;
        float wkc[DH], wvc[DH];
#pragma unroll
        for (int c = 0; c < DH; ++c) {
            wkc[c] = wk[c * DD + o];
            wvc[c] = wv[c * DD + o];
        }
        float bko = bk[o], bvo = bv[o], vsum = 0.f;
        for (int t = tid >> 6; t < T_; t += 4) {
            float ak0 = bko, ak1 = 0.f, av0 = bvo, av1 = 0.f;
#pragma unroll
            for (int c = 0; c < 8; ++c) {
                float x = Lf[t][c];
                ak0 += x * wkc[c]; av0 += x * wvc[c];
            }
#pragma unroll
            for (int c = 8; c < DH; ++c) {
                float x = Lf[t][c];
                ak1 += x * wkc[c]; av1 += x * wvc[c];
            }
            Ks[t][o] = fmaxf(ak0 + ak1, 0.f);
            float vv = fmaxf(av0 + av1, 0.f);
            Vs[t][o] = vv;
            vsum += vv;
        }
        Vp[tid >> 6][o] = vsum;
    }
    __syncthreads();
    if (tid < DD) Vcs[tid] = Vp[0][tid] + Vp[1][tid] + Vp[2][tid] + Vp[3][tid];
    __syncthreads();

    // attention
    {
        int h = tid >> 6;    // head
        int t = tid & 63;    // query row
        float q[DH];
#pragma unroll
        for (int c = 0; c < DH; ++c) {
            float a = bq[h * DH + c];                   // wave-uniform -> scalar
#pragma unroll
            for (int k = 0; k < DH; ++k)
                a += Lf[t][k] * wq[k * DD + h * DH + c];
            q[c] = fmaxf(a, 0.f);
        }
        float p[T_];
        float m = -1e30f;
#pragma unroll
        for (int s = 0; s < T_; ++s) {
            const float4* Kr = (const float4*)&Ks[s][h * DH];
            float4 k0 = Kr[0], k1 = Kr[1], k2 = Kr[2], k3 = Kr[3];
            float c0 = q[0]*k0.x + q[1]*k0.y + q[2]*k0.z + q[3]*k0.w;     // 4 indep 4-chains
            float c1 = q[4]*k1.x + q[5]*k1.y + q[6]*k1.z + q[7]*k1.w;
            float c2 = q[8]*k2.x + q[9]*k2.y + q[10]*k2.z + q[11]*k2.w;
            float c3 = q[12]*k3.x + q[13]*k3.y + q[14]*k3.z + q[15]*k3.w;
            float acc = ((c0 + c1) + (c2 + c3)) * 0.25f;
            p[s] = acc;
            m = fmaxf(m, acc);
        }
        float s0 = 0.f, s1 = 0.f, s2 = 0.f, s3 = 0.f;   // 4-way exp-sum
#pragma unroll
        for (int s = 0; s < T_; s += 4) {
            float e0 = __expf(p[s] - m);     p[s] = e0;     s0 += e0;
            float e1 = __expf(p[s+1] - m);   p[s+1] = e1;   s1 += e1;
            float e2 = __expf(p[s+2] - m);   p[s+2] = e2;   s2 += e2;
            float e3 = __expf(p[s+3] - m);   p[s+3] = e3;   s3 += e3;
        }
        float inv = 1.f / ((s0 + s1) + (s2 + s3));
        float r[DH];
#pragma unroll
        for (int c = 0; c < DH; ++c) r[c] = 0.f;
#pragma unroll
        for (int s = 0; s < T_; ++s) {
            float a = (s <= t) ? p[s] * inv - 1e-9f : 0.f;   // mask AFTER softmax; tail via Vcs
            const float4* Vr = (const float4*)&Vs[s][h * DH];
            float4 v0 = Vr[0], v1 = Vr[1], v2 = Vr[2], v3 = Vr[3];
            r[0] += a*v0.x; r[1] += a*v0.y; r[2] += a*v0.z; r[3] += a*v0.w;
            r[4] += a*v1.x; r[5] += a*v1.y; r[6] += a*v1.z; r[7] += a*v1.w;
            r[8] += a*v2.x; r[9] += a*v2.y; r[10] += a*v2.z; r[11] += a*v2.w;
            r[12] += a*v3.x; r[13] += a*v3.y; r[14] += a*v3.z; r[15] += a*v3.w;
        }
#pragma unroll
        for (int c = 0; c < DH; ++c) r[c] += 1e-9f * Vcs[h * DH + c];
        __syncthreads();           // all waves done reading Ks/Vs
        float4* Rr = (float4*)&Ks[t][h * DH];
        Rr[0] = make_float4(fmaxf(r[0],0.f),  fmaxf(r[1],0.f),  fmaxf(r[2],0.f),  fmaxf(r[3],0.f));
        Rr[1] = make_float4(fmaxf(r[4],0.f),  fmaxf(r[5],0.f),  fmaxf(r[6],0.f),  fmaxf(r[7],0.f));
        Rr[2] = make_float4(fmaxf(r[8],0.f),  fmaxf(r[9],0.f),  fmaxf(r[10],0.f), fmaxf(r[11],0.f));
        Rr[3] = make_float4(fmaxf(r[12],0.f), fmaxf(r[13],0.f), fmaxf(r[14],0.f), fmaxf(r[15],0.f));
    }
    __syncthreads();

    // output projection (64->16) + residual; 4 independent partial chains
    {
        int oo = tid & 15;
        float wl[DD];
#pragma unroll
        for (int k = 0; k < DD; ++k) wl[k] = wls[oo * DD + k];
        float bo = bls[oo];
        const float* Xsrc = X2 + (size_t)n * M_ + b * (T_ * DH);
        float* Ydst = ypre + (size_t)b * 332800 + (size_t)n * (T_ * DH);
        for (int tt = tid >> 4; tt < T_; tt += 16) {
            const float4* Rr = (const float4*)&Ks[tt][0];
            float a0 = 0.f, a1 = 0.f, a2 = 0.f, a3 = 0.f;
#pragma unroll
            for (int k4 = 0; k4 < 4; ++k4) {
                float4 rv = Rr[k4];
                a0 += wl[k4*4+0]*rv.x + wl[k4*4+1]*rv.y + wl[k4*4+2]*rv.z + wl[k4*4+3]*rv.w;
            }
#pragma unroll
            for (int k4 = 4; k4 < 8; ++k4) {
                float4 rv = Rr[k4];
                a1 += wl[k4*4+0]*rv.x + wl[k4*4+1]*rv.y + wl[k4*4+2]*rv.z + wl[k4*4+3]*rv.w;
            }
#pragma unroll
            for (int k4 = 8; k4 < 12; ++k4) {
                float4 rv = Rr[k4];
                a2 += wl[k4*4+0]*rv.x + wl[k4*4+1]*rv.y + wl[k4*4+2]*rv.z + wl[k4*4+3]*rv.w;
            }
#pragma unroll
            for (int k4 = 12; k4 < 16; ++k4) {
                float4 rv = Rr[k4];
                a3 += wl[k4*4+0]*rv.x + wl[k4*4+1]*rv.y + wl[k4*4+2]*rv.z + wl[k4*4+3]*rv.w;
            }
            float acc = bo + ((a0 + a1) + (a2 + a3));
            Ydst[tt * DH + oo] = Xsrc[tt * DH + oo] + fmaxf(acc, 0.f);
        }
    }
}

// ---------------- K5: per-batch partial sums (64 chunks per batch) -----------
__global__ __launch_bounds__(256) void k_lnpart(const float* __restrict__ y, float* __restrict__ part) {
    __shared__ float ssum[256], ssq[256];
    int b = blockIdx.x >> 6, chunk = blockIdx.x & 63;
    const float* yb = y + (size_t)b * 332800 + (size_t)chunk * 5200;
    float s = 0.f, q2 = 0.f;
    for (int i = threadIdx.x; i < 5200; i += 256) { float v = yb[i]; s += v; q2 += v * v; }
    ssum[threadIdx.x] = s; ssq[threadIdx.x] = q2;
    __syncthreads();
    for (int st = 128; st > 0; st >>= 1) {
        if (threadIdx.x < st) {
            ssum[threadIdx.x] += ssum[threadIdx.x + st];
            ssq[threadIdx.x] += ssq[threadIdx.x + st];
        }
        __syncthreads();
    }
    if (threadIdx.x == 0) { part[blockIdx.x * 2] = ssum[0]; part[blockIdx.x * 2 + 1] = ssq[0]; }
}

// ---------------- K6: stat finalize (folded) + normalize + gamma/beta --------
// y layout [b][n][t][c]; out layout [b][t][n][c]; gamma/beta (c,t,n)
__global__ __launch_bounds__(256) void k_lnapply(const float* __restrict__ y,
                                                 const float* __restrict__ part,
                                                 const float* __restrict__ gamma,
                                                 const float* __restrict__ beta,
                                                 float* __restrict__ out) {
    __shared__ float sred[2];
    int tid = threadIdx.x;
    int b = blockIdx.x / 1300;           // 1300 blocks per batch
    float s = 0.f, q = 0.f;
    if (tid < 64) { s = part[(b * 64 + tid) * 2]; q = part[(b * 64 + tid) * 2 + 1]; }
#pragma unroll
    for (int off = 32; off > 0; off >>= 1) { s += __shfl_down(s, off); q += __shfl_down(q, off); }
    if (tid == 0) {
        float mu = s / 332800.f;
        float var = q / 332800.f - mu * mu;
        sred[0] = mu; sred[1] = rsqrtf(var + 1e-5f);
    }
    __syncthreads();
    float mu = sred[0], rs = sred[1];
    int idx = blockIdx.x * 256 + tid;
    int r = idx - b * 332800;
    int n = r >> 10;
    int rr = r & 1023;
    int t = rr >> 4, c = rr & 15;
    int g = (c * T_ + t) * N_ + n;
    float v = (y[idx] - mu) * rs * gamma[g] + beta[g];
    out[(((size_t)(b * T_ + t) * N_) + n) * DH + c] = v;
}

extern "C" void kernel_launch(void* const* d_in, const int* in_sizes, int n_in,
                              void* d_out, int out_size, void* d_ws, size_t ws_size,
                              hipStream_t stream) {
    const float* in   = (const float*)d_in[0];
    const float* adj  = (const float*)d_in[1];
    const float* w_lt = (const float*)d_in[2];
    const float* b_lt = (const float*)d_in[3];
    const float* wq   = (const float*)d_in[4];
    const float* bq   = (const float*)d_in[5];
    const float* wk   = (const float*)d_in[6];
    const float* bk   = (const float*)d_in[7];
    const float* wv   = (const float*)d_in[8];
    const float* bv   = (const float*)d_in[9];
    const float* wls  = (const float*)d_in[10];
    const float* bls  = (const float*)d_in[11];
    const float* gam  = (const float*)d_in[12];
    const float* bet  = (const float*)d_in[13];
    float* out = (float*)d_out;

    float* ws = (float*)d_ws;
    float* S    = ws;                       // 105,625 -> pad 105,728
    float* X2   = S + 105728;               // 1,331,200  (layout n, bt, c)
    float* lfs2 = X2 + 1331200;             // 1,331,200  (layout n, bt, c)
    float* ypre = lfs2 + 1331200;           // 1,331,200  (layout b, n, t, c)
    float* part = ypre + 1331200;           // 512

    k_support<<<dim3(11, 11), 256, 0, stream>>>(adj, S);
    k_lintrans<<<(N_ * M_) / 1024, 256, 0, stream>>>(in, w_lt, b_lt, X2);
    k_gconv<<<dim3(16, 41), 256, 0, stream>>>(S, X2, lfs2);
    k_attn<<<B_ * N_, 256, 0, stream>>>(lfs2, X2, wq, bq, wk, bk, wv, bv, wls, bls, ypre);
    k_lnpart<<<256, 256, 0, stream>>>(ypre, part);
    k_lnapply<<<(B_ * T_ * N_ * DH) / 256, 256, 0, stream>>>(ypre, part, gam, bet, out);
}

// Round 8
// 117.324 us; speedup vs baseline: 1.6700x; 1.3898x over previous
//
#include <hip/hip_runtime.h>
#include <hip/hip_bf16.h>

#define B_ 4
#define T_ 64
#define N_ 325
#define F_ 3
#define DH 16
#define DD 64
#define NH 4
#define BT_ 256                 // B*T
#define M_ 4096                 // BT*DH  (GEMM N-dim)

using f16x4 = __attribute__((ext_vector_type(4))) _Float16;
using f32x4 = __attribute__((ext_vector_type(4))) float;
#define MFMA16 __builtin_amdgcn_mfma_f32_16x16x16f16

// ---------------- K1: S = adj + 2*adj@adj  (325x325) ------------------------
#define SBM 32
#define SBK 64
__global__ __launch_bounds__(256) void k_support(const float* __restrict__ adj, float* __restrict__ S) {
    __shared__ float As[SBK][33];
    __shared__ float Bs[SBK][33];
    int j0 = blockIdx.x * SBM, i0 = blockIdx.y * SBM;
    int tid = threadIdx.x;
    int ti = tid & 15, tj = tid >> 4;
    float a00 = 0.f, a01 = 0.f, a10 = 0.f, a11 = 0.f;
    for (int k0 = 0; k0 < N_; k0 += SBK) {
#pragma unroll
        for (int p = 0; p < 8; ++p) {
            int e = tid + p * 256;
            int k = e & 63, ii = e >> 6;
            int row = i0 + ii, col = k0 + k;
            As[k][ii] = (row < N_ && col < N_) ? adj[row * N_ + col] : 0.f;
        }
#pragma unroll
        for (int p = 0; p < 8; ++p) {
            int e = tid + p * 256;
            int jj = e & 31, k = e >> 5;
            int row = k0 + k, col = j0 + jj;
            Bs[k][jj] = (row < N_ && col < N_) ? adj[row * N_ + col] : 0.f;
        }
        __syncthreads();
#pragma unroll
        for (int k = 0; k < SBK; ++k) {
            float x0 = As[k][ti * 2], x1 = As[k][ti * 2 + 1];
            float y0 = Bs[k][tj * 2], y1 = Bs[k][tj * 2 + 1];
            a00 += x0 * y0; a01 += x0 * y1; a10 += x1 * y0; a11 += x1 * y1;
        }
        __syncthreads();
    }
    int i = i0 + ti * 2, j = j0 + tj * 2;
    if (i < N_ && j < N_)         S[i * N_ + j]           = adj[i * N_ + j]           + 2.f * a00;
    if (i < N_ && j + 1 < N_)     S[i * N_ + j + 1]       = adj[i * N_ + j + 1]       + 2.f * a01;
    if (i + 1 < N_ && j < N_)     S[(i + 1) * N_ + j]     = adj[(i + 1) * N_ + j]     + 2.f * a10;
    if (i + 1 < N_ && j + 1 < N_) S[(i + 1) * N_ + j + 1] = adj[(i + 1) * N_ + j + 1] + 2.f * a11;
}

// ---------------- K2: X2[n][bt][c] = relu(inputs @ w_lt^T + b_lt) ------------
__global__ void k_lintrans(const float* __restrict__ in,
                           const float* __restrict__ w,    // (16,3)
                           const float* __restrict__ bias, // (16)
                           float* __restrict__ X2) {
    int idx4 = (blockIdx.x * 256 + threadIdx.x) * 4;
    if (idx4 >= N_ * M_) return;
    int n = idx4 >> 12;
    int r = idx4 & 4095;
    int bt = r >> 4, c0 = r & 15;
    int tok = bt * N_ + n;
    float f0 = in[tok * 3 + 0];
    float f1 = in[tok * 3 + 1];
    float f2 = in[tok * 3 + 2];
    float4 o;
    o.x = fmaxf(bias[c0+0] + f0*w[(c0+0)*3+0] + f1*w[(c0+0)*3+1] + f2*w[(c0+0)*3+2], 0.f);
    o.y = fmaxf(bias[c0+1] + f0*w[(c0+1)*3+0] + f1*w[(c0+1)*3+1] + f2*w[(c0+1)*3+2], 0.f);
    o.z = fmaxf(bias[c0+2] + f0*w[(c0+2)*3+0] + f1*w[(c0+2)*3+1] + f2*w[(c0+2)*3+2], 0.f);
    o.w = fmaxf(bias[c0+3] + f0*w[(c0+3)*3+0] + f1*w[(c0+3)*3+1] + f2*w[(c0+3)*3+2], 0.f);
    *(float4*)&X2[idx4] = o;
}

// ---------------- K3: lfs2 = S @ X2 (scalar-broadcast GEMM) ------------------
#define GI 8
__global__ __launch_bounds__(256) void k_gconv(const float* __restrict__ S,
                                               const float* __restrict__ X2,
                                               float* __restrict__ lfs2) {
    int m = blockIdx.x * 256 + threadIdx.x;
    int i0 = blockIdx.y * GI;
    float acc[GI];
#pragma unroll
    for (int r = 0; r < GI; ++r) acc[r] = 0.f;
#pragma unroll 8
    for (int k = 0; k < N_; ++k) {
        float x = X2[(size_t)k * M_ + m];
#pragma unroll
        for (int r = 0; r < GI; ++r)
            acc[r] += S[(i0 + r) * N_ + k] * x;   // uniform addr -> s_load
    }
    int rows = N_ - i0; if (rows > GI) rows = GI;
    for (int r = 0; r < rows; ++r)
        lfs2[(size_t)(i0 + r) * M_ + m] = acc[r];
}

// ---------------- K4: MFMA attention, fully fused ----------------------------
// block = (b,n); wave = head. Transposed-compute chain: all fragments flow
// between MFMAs with zero shuffles (D-layout == B-layout; D as A == transpose).
__global__ __launch_bounds__(256) void k_attn(
    const float* __restrict__ lfs2, const float* __restrict__ X2,
    const float* __restrict__ wq, const float* __restrict__ bq,
    const float* __restrict__ wk, const float* __restrict__ bk,
    const float* __restrict__ wv, const float* __restrict__ bv,
    const float* __restrict__ wls, const float* __restrict__ bls,
    float* __restrict__ ypre, float* __restrict__ part) {
    __shared__ __align__(16) float Lf[T_ * 20];     // 5.1 KB, stride 20
    __shared__ __align__(16) float Rs[NH][T_][20];  // 20.5 KB per-head resp^T
    __shared__ float lnp[NH][2];
    int bn = blockIdx.x;
    int b = bn / N_, n = bn % N_;
    int tid = threadIdx.x;
    int h = tid >> 6;          // wave = head
    int l = tid & 63;
    int lr = l & 15, kg = l >> 4;

    const float* Lsrc = lfs2 + (size_t)n * M_ + b * (T_ * DH);  // 1024 contiguous
    for (int i = tid; i < T_ * DH; i += 256) Lf[(i >> 4) * 20 + (i & 15)] = Lsrc[i];
    __syncthreads();

    // Lf fragments: elem j = Lf[lr+16q][kg*4+j]  (valid as A of Lf AND B of Lf^T)
    f16x4 lff[4];
#pragma unroll
    for (int q = 0; q < 4; ++q) {
        const float4 v = *(const float4*)&Lf[(lr + 16 * q) * 20 + kg * 4];
        f16x4 t; t[0] = (_Float16)v.x; t[1] = (_Float16)v.y; t[2] = (_Float16)v.z; t[3] = (_Float16)v.w;
        lff[q] = t;
    }
    // weight fragments: w[k*64 + h*16 + c], k=kg*4+j, c=lr (A of W^T; B of W)
    f16x4 wqf, wkf, wvf;
    {
        int base = h * 16 + lr;
#pragma unroll
        for (int j = 0; j < 4; ++j) {
            wqf[j] = (_Float16)wq[(kg * 4 + j) * DD + base];
            wkf[j] = (_Float16)wk[(kg * 4 + j) * DD + base];
            wvf[j] = (_Float16)wv[(kg * 4 + j) * DD + base];
        }
    }
    f32x4 zero = {0.f, 0.f, 0.f, 0.f};

    // Q^T = Wq^T@Lf^T (scaled by 1/4), K^T = Wk^T@Lf^T, V = Lf@Wv ; bias+relu
    f16x4 qtf[4], ktf[4], vvf[4];
    {
        float bqr[4], bkr[4];
#pragma unroll
        for (int r = 0; r < 4; ++r) { bqr[r] = bq[h * 16 + kg * 4 + r]; bkr[r] = bk[h * 16 + kg * 4 + r]; }
        float bvc = bv[h * 16 + lr];
#pragma unroll
        for (int q = 0; q < 4; ++q) {
            f32x4 qa = MFMA16(wqf, lff[q], zero, 0, 0, 0);
            f32x4 ka = MFMA16(wkf, lff[q], zero, 0, 0, 0);
            f32x4 va = MFMA16(lff[q], wvf, zero, 0, 0, 0);
#pragma unroll
            for (int r = 0; r < 4; ++r) {
                qtf[q][r] = (_Float16)(fmaxf(qa[r] + bqr[r], 0.f) * 0.25f);  // fold 1/sqrt(16)
                ktf[q][r] = (_Float16)fmaxf(ka[r] + bkr[r], 0.f);
                vvf[q][r] = (_Float16)fmaxf(va[r] + bvc, 0.f);
            }
        }
    }
    // S^T tiles = K @ Q^T : lane holds S^T[s=ss*16+kg*4+r][t=tt*16+lr]
    f32x4 st[4][4];
#pragma unroll
    for (int ss = 0; ss < 4; ++ss)
#pragma unroll
        for (int tt = 0; tt < 4; ++tt)
            st[ss][tt] = MFMA16(ktf[ss], qtf[tt], zero, 0, 0, 0);

    // softmax over s: LANE-LOCAL 16 values; mask AFTER softmax (masked -> 0,
    // the 1e-9 tail contributes <=1e-8 to output: below noise)
    f16x4 pf[4][4];
#pragma unroll
    for (int tt = 0; tt < 4; ++tt) {
        int t = tt * 16 + lr;
        float m = -1e30f;
#pragma unroll
        for (int ss = 0; ss < 4; ++ss)
#pragma unroll
            for (int r = 0; r < 4; ++r) m = fmaxf(m, st[ss][tt][r]);
        float e[4][4];
        float sum = 0.f;
#pragma unroll
        for (int ss = 0; ss < 4; ++ss)
#pragma unroll
            for (int r = 0; r < 4; ++r) { float ev = __expf(st[ss][tt][r] - m); e[ss][r] = ev; sum += ev; }
        float inv = 1.f / sum;
#pragma unroll
        for (int ss = 0; ss < 4; ++ss)
#pragma unroll
            for (int r = 0; r < 4; ++r) {
                int s = ss * 16 + kg * 4 + r;
                pf[ss][tt][r] = (s <= t) ? (_Float16)(e[ss][r] * inv) : (_Float16)0.f;
            }
    }
    // R^T = V^T @ P^T (K=64 via 4 accumulating MFMAs), relu
    f16x4 rtf[4];
#pragma unroll
    for (int tt = 0; tt < 4; ++tt) {
        f32x4 acc = zero;
#pragma unroll
        for (int ss = 0; ss < 4; ++ss)
            acc = MFMA16(vvf[ss], pf[ss][tt], acc, 0, 0, 0);
#pragma unroll
        for (int r = 0; r < 4; ++r) rtf[tt][r] = (_Float16)fmaxf(acc[r], 0.f);
    }
    // resp^T = Wls_h @ R^T ; stage to LDS for cross-head sum
    f16x4 wlf;
    {
        const float4 w4 = *(const float4*)&wls[lr * DD + h * 16 + kg * 4];
        wlf[0] = (_Float16)w4.x; wlf[1] = (_Float16)w4.y; wlf[2] = (_Float16)w4.z; wlf[3] = (_Float16)w4.w;
    }
#pragma unroll
    for (int tt = 0; tt < 4; ++tt) {
        f32x4 rp = MFMA16(wlf, rtf[tt], zero, 0, 0, 0);
        float4 o4; o4.x = rp[0]; o4.y = rp[1]; o4.z = rp[2]; o4.w = rp[3];
        *(float4*)&Rs[h][tt * 16 + lr][kg * 4] = o4;   // Rs[h][t][o0..o0+3]
    }
    __syncthreads();

    // epilogue: cross-head sum + bls + relu + residual + LN partials
    {
        int t = tid >> 2, o0 = (tid & 3) * 4;
        float4 r0 = *(const float4*)&Rs[0][t][o0];
        float4 r1 = *(const float4*)&Rs[1][t][o0];
        float4 r2 = *(const float4*)&Rs[2][t][o0];
        float4 r3 = *(const float4*)&Rs[3][t][o0];
        const float* Xsrc = X2 + (size_t)n * M_ + b * (T_ * DH);
        float4 xv = *(const float4*)&Xsrc[t * DH + o0];
        float y0 = xv.x + fmaxf(r0.x + r1.x + r2.x + r3.x + bls[o0 + 0], 0.f);
        float y1 = xv.y + fmaxf(r0.y + r1.y + r2.y + r3.y + bls[o0 + 1], 0.f);
        float y2 = xv.z + fmaxf(r0.z + r1.z + r2.z + r3.z + bls[o0 + 2], 0.f);
        float y3 = xv.w + fmaxf(r0.w + r1.w + r2.w + r3.w + bls[o0 + 3], 0.f);
        float4 yv; yv.x = y0; yv.y = y1; yv.z = y2; yv.w = y3;
        *(float4*)&ypre[(size_t)b * 332800 + (size_t)n * 1024 + t * DH + o0] = yv;
        float ls = (y0 + y1) + (y2 + y3);
        float lq = (y0 * y0 + y1 * y1) + (y2 * y2 + y3 * y3);
#pragma unroll
        for (int off = 32; off > 0; off >>= 1) { ls += __shfl_down(ls, off); lq += __shfl_down(lq, off); }
        if (l == 0) { lnp[h][0] = ls; lnp[h][1] = lq; }
    }
    __syncthreads();
    if (tid == 0) {
        part[bn * 2]     = (lnp[0][0] + lnp[1][0]) + (lnp[2][0] + lnp[3][0]);
        part[bn * 2 + 1] = (lnp[0][1] + lnp[1][1]) + (lnp[2][1] + lnp[3][1]);
    }
}

// ---------------- K5: reduce 325 per-block partials -> mu/rsigma per batch ---
__global__ __launch_bounds__(256) void k_lnstat(const float* __restrict__ part, float* __restrict__ stat) {
    __shared__ float ssum[256], ssq[256];
    int b = blockIdx.x, tid = threadIdx.x;
    float s = 0.f, q = 0.f;
    for (int i = tid; i < N_; i += 256) {
        s += part[(b * N_ + i) * 2];
        q += part[(b * N_ + i) * 2 + 1];
    }
    ssum[tid] = s; ssq[tid] = q;
    __syncthreads();
    for (int st = 128; st > 0; st >>= 1) {
        if (tid < st) { ssum[tid] += ssum[tid + st]; ssq[tid] += ssq[tid + st]; }
        __syncthreads();
    }
    if (tid == 0) {
        float mu = ssum[0] / 332800.f;
        float var = ssq[0] / 332800.f - mu * mu;
        stat[b * 2] = mu;
        stat[b * 2 + 1] = rsqrtf(var + 1e-5f);
    }
}

// ---------------- K6: normalize + gamma/beta ---------------------------------
// y layout [b][n][t][c]; out layout [b][t][n][c]; gamma/beta (c,t,n)
__global__ __launch_bounds__(256) void k_lnapply(const float* __restrict__ y,
                                                 const float* __restrict__ stat,
                                                 const float* __restrict__ gamma,
                                                 const float* __restrict__ beta,
                                                 float* __restrict__ out) {
    int tid = threadIdx.x;
    int idx = blockIdx.x * 256 + tid;
    int b = idx / 332800;
    float mu = stat[b * 2], rs = stat[b * 2 + 1];
    int r = idx - b * 332800;
    int n = r >> 10;
    int rr = r & 1023;
    int t = rr >> 4, c = rr & 15;
    int g = (c * T_ + t) * N_ + n;
    float v = (y[idx] - mu) * rs * gamma[g] + beta[g];
    out[(((size_t)(b * T_ + t) * N_) + n) * DH + c] = v;
}

extern "C" void kernel_launch(void* const* d_in, const int* in_sizes, int n_in,
                              void* d_out, int out_size, void* d_ws, size_t ws_size,
                              hipStream_t stream) {
    const float* in   = (const float*)d_in[0];
    const float* adj  = (const float*)d_in[1];
    const float* w_lt = (const float*)d_in[2];
    const float* b_lt = (const float*)d_in[3];
    const float* wq   = (const float*)d_in[4];
    const float* bq   = (const float*)d_in[5];
    const float* wk   = (const float*)d_in[6];
    const float* bk   = (const float*)d_in[7];
    const float* wv   = (const float*)d_in[8];
    const float* bv   = (const float*)d_in[9];
    const float* wls  = (const float*)d_in[10];
    const float* bls  = (const float*)d_in[11];
    const float* gam  = (const float*)d_in[12];
    const float* bet  = (const float*)d_in[13];
    float* out = (float*)d_out;

    float* ws = (float*)d_ws;
    float* S    = ws;                       // 105,625 -> pad 105,728
    float* X2   = S + 105728;               // 1,331,200  (layout n, bt, c)
    float* lfs2 = X2 + 1331200;             // 1,331,200  (layout n, bt, c)
    float* ypre = lfs2 + 1331200;           // 1,331,200  (layout b, n, t, c)
    float* part = ypre + 1331200;           // 2600 (per (b,n): sum, sumsq)
    float* stat = part + 2608;              // 8

    k_support<<<dim3(11, 11), 256, 0, stream>>>(adj, S);
    k_lintrans<<<(N_ * M_) / 1024, 256, 0, stream>>>(in, w_lt, b_lt, X2);
    k_gconv<<<dim3(16, 41), 256, 0, stream>>>(S, X2, lfs2);
    k_attn<<<B_ * N_, 256, 0, stream>>>(lfs2, X2, wq, bq, wk, bk, wv, bv, wls, bls, ypre, part);
    k_lnstat<<<4, 256, 0, stream>>>(part, stat);
    k_lnapply<<<(B_ * T_ * N_ * DH) / 256, 256, 0, stream>>>(ypre, stat, gam, bet, out);
}

// Round 9
// 96.811 us; speedup vs baseline: 2.0238x; 1.2119x over previous
//
#include <hip/hip_runtime.h>
#include <hip/hip_bf16.h>

#define B_ 4
#define T_ 64
#define N_ 325
#define NP 336                  // padded graph dim for MFMA gconv
#define F_ 3
#define DH 16
#define DD 64
#define NH 4
#define BT_ 256                 // B*T
#define M_ 4096                 // BT*DH  (GEMM N-dim)

using f16x4 = __attribute__((ext_vector_type(4))) _Float16;
using f32x4 = __attribute__((ext_vector_type(4))) float;
#define MFMA16 __builtin_amdgcn_mfma_f32_16x16x16f16

// ---------------- K1: S16 = f16(adj + 2*adj@adj)  (325x325, padded 336) ------
#define SBM 32
#define SBK 64
__global__ __launch_bounds__(256) void k_support(const float* __restrict__ adj, _Float16* __restrict__ S16) {
    __shared__ float As[SBK][33];
    __shared__ float Bs[SBK][33];
    int j0 = blockIdx.x * SBM, i0 = blockIdx.y * SBM;
    int tid = threadIdx.x;
    int ti = tid & 15, tj = tid >> 4;
    float a00 = 0.f, a01 = 0.f, a10 = 0.f, a11 = 0.f;
    for (int k0 = 0; k0 < N_; k0 += SBK) {
#pragma unroll
        for (int p = 0; p < 8; ++p) {
            int e = tid + p * 256;
            int k = e & 63, ii = e >> 6;
            int row = i0 + ii, col = k0 + k;
            As[k][ii] = (row < N_ && col < N_) ? adj[row * N_ + col] : 0.f;
        }
#pragma unroll
        for (int p = 0; p < 8; ++p) {
            int e = tid + p * 256;
            int jj = e & 31, k = e >> 5;
            int row = k0 + k, col = j0 + jj;
            Bs[k][jj] = (row < N_ && col < N_) ? adj[row * N_ + col] : 0.f;
        }
        __syncthreads();
#pragma unroll
        for (int k = 0; k < SBK; ++k) {
            float x0 = As[k][ti * 2], x1 = As[k][ti * 2 + 1];
            float y0 = Bs[k][tj * 2], y1 = Bs[k][tj * 2 + 1];
            a00 += x0 * y0; a01 += x0 * y1; a10 += x1 * y0; a11 += x1 * y1;
        }
        __syncthreads();
    }
    int i = i0 + ti * 2, j = j0 + tj * 2;
    if (i < N_ && j < N_)         S16[i * NP + j]           = (_Float16)(adj[i * N_ + j]           + 2.f * a00);
    if (i < N_ && j + 1 < N_)     S16[i * NP + j + 1]       = (_Float16)(adj[i * N_ + j + 1]       + 2.f * a01);
    if (i + 1 < N_ && j < N_)     S16[(i + 1) * NP + j]     = (_Float16)(adj[(i + 1) * N_ + j]     + 2.f * a10);
    if (i + 1 < N_ && j + 1 < N_) S16[(i + 1) * NP + j + 1] = (_Float16)(adj[(i + 1) * N_ + j + 1] + 2.f * a11);
}

// ---------------- K2: X2 (f32 [n][m]) + X2T (f16 [m][kpad]) ------------------
__global__ void k_lintrans(const float* __restrict__ in,
                           const float* __restrict__ w,    // (16,3)
                           const float* __restrict__ bias, // (16)
                           float* __restrict__ X2, _Float16* __restrict__ X2T) {
    int idx4 = (blockIdx.x * 256 + threadIdx.x) * 4;
    if (idx4 >= N_ * M_) return;
    int n = idx4 >> 12;
    int r = idx4 & 4095;          // m = bt*16 + c0
    int bt = r >> 4, c0 = r & 15;
    int tok = bt * N_ + n;
    float f0 = in[tok * 3 + 0];
    float f1 = in[tok * 3 + 1];
    float f2 = in[tok * 3 + 2];
    float4 o;
    o.x = fmaxf(bias[c0+0] + f0*w[(c0+0)*3+0] + f1*w[(c0+0)*3+1] + f2*w[(c0+0)*3+2], 0.f);
    o.y = fmaxf(bias[c0+1] + f0*w[(c0+1)*3+0] + f1*w[(c0+1)*3+1] + f2*w[(c0+1)*3+2], 0.f);
    o.z = fmaxf(bias[c0+2] + f0*w[(c0+2)*3+0] + f1*w[(c0+2)*3+1] + f2*w[(c0+2)*3+2], 0.f);
    o.w = fmaxf(bias[c0+3] + f0*w[(c0+3)*3+0] + f1*w[(c0+3)*3+1] + f2*w[(c0+3)*3+2], 0.f);
    *(float4*)&X2[idx4] = o;
    X2T[(size_t)(r + 0) * NP + n] = (_Float16)o.x;
    X2T[(size_t)(r + 1) * NP + n] = (_Float16)o.y;
    X2T[(size_t)(r + 2) * NP + n] = (_Float16)o.z;
    X2T[(size_t)(r + 3) * NP + n] = (_Float16)o.w;
}

// ---------------- K3: lfs2 = S @ X2  — f16 MFMA, in-block split-K ------------
// block: 16 i-rows x 64 m-cols; 4 waves take k-quarters; LDS reduce.
__global__ __launch_bounds__(256) void k_gconv(const _Float16* __restrict__ S16,
                                               const _Float16* __restrict__ X2T,
                                               float* __restrict__ lfs2) {
    __shared__ __align__(16) float red[4][16][68];
    int m0 = blockIdx.x * 64;
    int i0 = blockIdx.y * 16;
    int tid = threadIdx.x;
    int w = tid >> 6, l = tid & 63;
    int lr = l & 15, kg = l >> 4;

    int c0 = w * 5;
    int nc = (w == 3) ? 6 : 5;    // 21 chunks of K=16 total (336 = NP)

    f32x4 acc0 = {0.f,0.f,0.f,0.f}, acc1 = acc0, acc2 = acc0, acc3 = acc0;
    const size_t arow = (size_t)(i0 + lr) * NP;
    for (int cc = 0; cc < nc; ++cc) {
        int k = (c0 + cc) * 16 + kg * 4;
        f16x4 af = *(const f16x4*)&S16[arow + k];
        f16x4 b0 = *(const f16x4*)&X2T[(size_t)(m0 + lr) * NP + k];
        f16x4 b1 = *(const f16x4*)&X2T[(size_t)(m0 + 16 + lr) * NP + k];
        f16x4 b2 = *(const f16x4*)&X2T[(size_t)(m0 + 32 + lr) * NP + k];
        f16x4 b3 = *(const f16x4*)&X2T[(size_t)(m0 + 48 + lr) * NP + k];
        acc0 = MFMA16(af, b0, acc0, 0, 0, 0);
        acc1 = MFMA16(af, b1, acc1, 0, 0, 0);
        acc2 = MFMA16(af, b2, acc2, 0, 0, 0);
        acc3 = MFMA16(af, b3, acc3, 0, 0, 0);
    }
#pragma unroll
    for (int r = 0; r < 4; ++r) {
        red[w][kg * 4 + r][ 0 + lr] = acc0[r];
        red[w][kg * 4 + r][16 + lr] = acc1[r];
        red[w][kg * 4 + r][32 + lr] = acc2[r];
        red[w][kg * 4 + r][48 + lr] = acc3[r];
    }
    __syncthreads();
    int row = tid >> 4, col = (tid & 15) * 4;
    if (i0 + row < N_) {
        float4 p0 = *(const float4*)&red[0][row][col];
        float4 p1 = *(const float4*)&red[1][row][col];
        float4 p2 = *(const float4*)&red[2][row][col];
        float4 p3 = *(const float4*)&red[3][row][col];
        float4 o;
        o.x = (p0.x + p1.x) + (p2.x + p3.x);
        o.y = (p0.y + p1.y) + (p2.y + p3.y);
        o.z = (p0.z + p1.z) + (p2.z + p3.z);
        o.w = (p0.w + p1.w) + (p2.w + p3.w);
        *(float4*)&lfs2[(size_t)(i0 + row) * M_ + m0 + col] = o;
    }
}

// ---------------- K4: MFMA attention, fully fused (unchanged r8) -------------
__global__ __launch_bounds__(256) void k_attn(
    const float* __restrict__ lfs2, const float* __restrict__ X2,
    const float* __restrict__ wq, const float* __restrict__ bq,
    const float* __restrict__ wk, const float* __restrict__ bk,
    const float* __restrict__ wv, const float* __restrict__ bv,
    const float* __restrict__ wls, const float* __restrict__ bls,
    float* __restrict__ ypre, float* __restrict__ part) {
    __shared__ __align__(16) float Lf[T_ * 20];
    __shared__ __align__(16) float Rs[NH][T_][20];
    __shared__ float lnp[NH][2];
    int bn = blockIdx.x;
    int b = bn / N_, n = bn % N_;
    int tid = threadIdx.x;
    int h = tid >> 6;
    int l = tid & 63;
    int lr = l & 15, kg = l >> 4;

    const float* Lsrc = lfs2 + (size_t)n * M_ + b * (T_ * DH);
    for (int i = tid; i < T_ * DH; i += 256) Lf[(i >> 4) * 20 + (i & 15)] = Lsrc[i];
    __syncthreads();

    f16x4 lff[4];
#pragma unroll
    for (int q = 0; q < 4; ++q) {
        const float4 v = *(const float4*)&Lf[(lr + 16 * q) * 20 + kg * 4];
        f16x4 t; t[0] = (_Float16)v.x; t[1] = (_Float16)v.y; t[2] = (_Float16)v.z; t[3] = (_Float16)v.w;
        lff[q] = t;
    }
    f16x4 wqf, wkf, wvf;
    {
        int base = h * 16 + lr;
#pragma unroll
        for (int j = 0; j < 4; ++j) {
            wqf[j] = (_Float16)wq[(kg * 4 + j) * DD + base];
            wkf[j] = (_Float16)wk[(kg * 4 + j) * DD + base];
            wvf[j] = (_Float16)wv[(kg * 4 + j) * DD + base];
        }
    }
    f32x4 zero = {0.f, 0.f, 0.f, 0.f};

    f16x4 qtf[4], ktf[4], vvf[4];
    {
        float bqr[4], bkr[4];
#pragma unroll
        for (int r = 0; r < 4; ++r) { bqr[r] = bq[h * 16 + kg * 4 + r]; bkr[r] = bk[h * 16 + kg * 4 + r]; }
        float bvc = bv[h * 16 + lr];
#pragma unroll
        for (int q = 0; q < 4; ++q) {
            f32x4 qa = MFMA16(wqf, lff[q], zero, 0, 0, 0);
            f32x4 ka = MFMA16(wkf, lff[q], zero, 0, 0, 0);
            f32x4 va = MFMA16(lff[q], wvf, zero, 0, 0, 0);
#pragma unroll
            for (int r = 0; r < 4; ++r) {
                qtf[q][r] = (_Float16)(fmaxf(qa[r] + bqr[r], 0.f) * 0.25f);
                ktf[q][r] = (_Float16)fmaxf(ka[r] + bkr[r], 0.f);
                vvf[q][r] = (_Float16)fmaxf(va[r] + bvc, 0.f);
            }
        }
    }
    f32x4 st[4][4];
#pragma unroll
    for (int ss = 0; ss < 4; ++ss)
#pragma unroll
        for (int tt = 0; tt < 4; ++tt)
            st[ss][tt] = MFMA16(ktf[ss], qtf[tt], zero, 0, 0, 0);

    f16x4 pf[4][4];
#pragma unroll
    for (int tt = 0; tt < 4; ++tt) {
        int t = tt * 16 + lr;
        float m = -1e30f;
#pragma unroll
        for (int ss = 0; ss < 4; ++ss)
#pragma unroll
            for (int r = 0; r < 4; ++r) m = fmaxf(m, st[ss][tt][r]);
        float e[4][4];
        float sum = 0.f;
#pragma unroll
        for (int ss = 0; ss < 4; ++ss)
#pragma unroll
            for (int r = 0; r < 4; ++r) { float ev = __expf(st[ss][tt][r] - m); e[ss][r] = ev; sum += ev; }
        float inv = 1.f / sum;
#pragma unroll
        for (int ss = 0; ss < 4; ++ss)
#pragma unroll
            for (int r = 0; r < 4; ++r) {
                int s = ss * 16 + kg * 4 + r;
                pf[ss][tt][r] = (s <= t) ? (_Float16)(e[ss][r] * inv) : (_Float16)0.f;
            }
    }
    f16x4 rtf[4];
#pragma unroll
    for (int tt = 0; tt < 4; ++tt) {
        f32x4 acc = zero;
#pragma unroll
        for (int ss = 0; ss < 4; ++ss)
            acc = MFMA16(vvf[ss], pf[ss][tt], acc, 0, 0, 0);
#pragma unroll
        for (int r = 0; r < 4; ++r) rtf[tt][r] = (_Float16)fmaxf(acc[r], 0.f);
    }
    f16x4 wlf;
    {
        const float4 w4 = *(const float4*)&wls[lr * DD + h * 16 + kg * 4];
        wlf[0] = (_Float16)w4.x; wlf[1] = (_Float16)w4.y; wlf[2] = (_Float16)w4.z; wlf[3] = (_Float16)w4.w;
    }
#pragma unroll
    for (int tt = 0; tt < 4; ++tt) {
        f32x4 rp = MFMA16(wlf, rtf[tt], zero, 0, 0, 0);
        float4 o4; o4.x = rp[0]; o4.y = rp[1]; o4.z = rp[2]; o4.w = rp[3];
        *(float4*)&Rs[h][tt * 16 + lr][kg * 4] = o4;
    }
    __syncthreads();

    {
        int t = tid >> 2, o0 = (tid & 3) * 4;
        float4 r0 = *(const float4*)&Rs[0][t][o0];
        float4 r1 = *(const float4*)&Rs[1][t][o0];
        float4 r2 = *(const float4*)&Rs[2][t][o0];
        float4 r3 = *(const float4*)&Rs[3][t][o0];
        const float* Xsrc = X2 + (size_t)n * M_ + b * (T_ * DH);
        float4 xv = *(const float4*)&Xsrc[t * DH + o0];
        float y0 = xv.x + fmaxf(r0.x + r1.x + r2.x + r3.x + bls[o0 + 0], 0.f);
        float y1 = xv.y + fmaxf(r0.y + r1.y + r2.y + r3.y + bls[o0 + 1], 0.f);
        float y2 = xv.z + fmaxf(r0.z + r1.z + r2.z + r3.z + bls[o0 + 2], 0.f);
        float y3 = xv.w + fmaxf(r0.w + r1.w + r2.w + r3.w + bls[o0 + 3], 0.f);
        float4 yv; yv.x = y0; yv.y = y1; yv.z = y2; yv.w = y3;
        *(float4*)&ypre[(size_t)b * 332800 + (size_t)n * 1024 + t * DH + o0] = yv;
        float ls = (y0 + y1) + (y2 + y3);
        float lq = (y0 * y0 + y1 * y1) + (y2 * y2 + y3 * y3);
#pragma unroll
        for (int off = 32; off > 0; off >>= 1) { ls += __shfl_down(ls, off); lq += __shfl_down(lq, off); }
        if (l == 0) { lnp[h][0] = ls; lnp[h][1] = lq; }
    }
    __syncthreads();
    if (tid == 0) {
        part[bn * 2]     = (lnp[0][0] + lnp[1][0]) + (lnp[2][0] + lnp[3][0]);
        part[bn * 2 + 1] = (lnp[0][1] + lnp[1][1]) + (lnp[2][1] + lnp[3][1]);
    }
}

// ---------------- K5: reduce 325 per-block partials -> mu/rsigma per batch ---
__global__ __launch_bounds__(256) void k_lnstat(const float* __restrict__ part, float* __restrict__ stat) {
    __shared__ float ssum[256], ssq[256];
    int b = blockIdx.x, tid = threadIdx.x;
    float s = 0.f, q = 0.f;
    for (int i = tid; i < N_; i += 256) {
        s += part[(b * N_ + i) * 2];
        q += part[(b * N_ + i) * 2 + 1];
    }
    ssum[tid] = s; ssq[tid] = q;
    __syncthreads();
    for (int st = 128; st > 0; st >>= 1) {
        if (tid < st) { ssum[tid] += ssum[tid + st]; ssq[tid] += ssq[tid + st]; }
        __syncthreads();
    }
    if (tid == 0) {
        float mu = ssum[0] / 332800.f;
        float var = ssq[0] / 332800.f - mu * mu;
        stat[b * 2] = mu;
        stat[b * 2 + 1] = rsqrtf(var + 1e-5f);
    }
}

// ---------------- K6: normalize + gamma/beta ---------------------------------
__global__ __launch_bounds__(256) void k_lnapply(const float* __restrict__ y,
                                                 const float* __restrict__ stat,
                                                 const float* __restrict__ gamma,
                                                 const float* __restrict__ beta,
                                                 float* __restrict__ out) {
    int tid = threadIdx.x;
    int idx = blockIdx.x * 256 + tid;
    int b = idx / 332800;
    float mu = stat[b * 2], rs = stat[b * 2 + 1];
    int r = idx - b * 332800;
    int n = r >> 10;
    int rr = r & 1023;
    int t = rr >> 4, c = rr & 15;
    int g = (c * T_ + t) * N_ + n;
    float v = (y[idx] - mu) * rs * gamma[g] + beta[g];
    out[(((size_t)(b * T_ + t) * N_) + n) * DH + c] = v;
}

extern "C" void kernel_launch(void* const* d_in, const int* in_sizes, int n_in,
                              void* d_out, int out_size, void* d_ws, size_t ws_size,
                              hipStream_t stream) {
    const float* in   = (const float*)d_in[0];
    const float* adj  = (const float*)d_in[1];
    const float* w_lt = (const float*)d_in[2];
    const float* b_lt = (const float*)d_in[3];
    const float* wq   = (const float*)d_in[4];
    const float* bq   = (const float*)d_in[5];
    const float* wk   = (const float*)d_in[6];
    const float* bk   = (const float*)d_in[7];
    const float* wv   = (const float*)d_in[8];
    const float* bv   = (const float*)d_in[9];
    const float* wls  = (const float*)d_in[10];
    const float* bls  = (const float*)d_in[11];
    const float* gam  = (const float*)d_in[12];
    const float* bet  = (const float*)d_in[13];
    float* out = (float*)d_out;

    float* ws = (float*)d_ws;
    _Float16* S16 = (_Float16*)ws;                 // 336*336 f16 = 56,448 f32-slots
    float* X2   = ws + 56576;                      // 1,331,200  (f32 [n][m])
    _Float16* X2T = (_Float16*)(X2 + 1331200);     // 4096*336 f16 = 688,128 f32-slots
    float* lfs2 = X2 + 1331200 + 688128;           // 1,331,200
    float* ypre = lfs2 + 1331200;                  // 1,331,200
    float* part = ypre + 1331200;                  // 2600
    float* stat = part + 2608;                     // 8

    hipMemsetAsync(S16, 0, (size_t)NP * NP * 2, stream);
    hipMemsetAsync(X2T, 0, (size_t)M_ * NP * 2, stream);
    k_support<<<dim3(11, 11), 256, 0, stream>>>(adj, S16);
    k_lintrans<<<(N_ * M_) / 1024, 256, 0, stream>>>(in, w_lt, b_lt, X2, X2T);
    k_gconv<<<dim3(64, 21), 256, 0, stream>>>(S16, X2T, lfs2);
    k_attn<<<B_ * N_, 256, 0, stream>>>(lfs2, X2, wq, bq, wk, bk, wv, bv, wls, bls, ypre, part);
    k_lnstat<<<4, 256, 0, stream>>>(part, stat);
    k_lnapply<<<(B_ * T_ * N_ * DH) / 256, 256, 0, stream>>>(ypre, stat, gam, bet, out);
}

// Round 10
// 82.592 us; speedup vs baseline: 2.3722x; 1.1722x over previous
//
#include <hip/hip_runtime.h>
#include <hip/hip_bf16.h>

#define B_ 4
#define T_ 64
#define N_ 325
#define NP 336                  // padded graph dim for MFMA gconv
#define F_ 3
#define DH 16
#define DD 64
#define NH 4
#define BT_ 256                 // B*T
#define M_ 4096                 // BT*DH  (GEMM N-dim)

using f16x4 = __attribute__((ext_vector_type(4))) _Float16;
using f32x4 = __attribute__((ext_vector_type(4))) float;
#define MFMA16 __builtin_amdgcn_mfma_f32_16x16x16f16

// ---------------- K1: S16 = f16(adj + 2*adj@adj), pads zeroed in-kernel ------
#define SBM 32
#define SBK 64
__global__ __launch_bounds__(256) void k_support(const float* __restrict__ adj, _Float16* __restrict__ S16) {
    __shared__ float As[SBK][33];
    __shared__ float Bs[SBK][33];
    int j0 = blockIdx.x * SBM, i0 = blockIdx.y * SBM;
    int tid = threadIdx.x;
    int ti = tid & 15, tj = tid >> 4;
    float a00 = 0.f, a01 = 0.f, a10 = 0.f, a11 = 0.f;
    for (int k0 = 0; k0 < N_; k0 += SBK) {
#pragma unroll
        for (int p = 0; p < 8; ++p) {
            int e = tid + p * 256;
            int k = e & 63, ii = e >> 6;
            int row = i0 + ii, col = k0 + k;
            As[k][ii] = (row < N_ && col < N_) ? adj[row * N_ + col] : 0.f;
        }
#pragma unroll
        for (int p = 0; p < 8; ++p) {
            int e = tid + p * 256;
            int jj = e & 31, k = e >> 5;
            int row = k0 + k, col = j0 + jj;
            Bs[k][jj] = (row < N_ && col < N_) ? adj[row * N_ + col] : 0.f;
        }
        __syncthreads();
#pragma unroll
        for (int k = 0; k < SBK; ++k) {
            float x0 = As[k][ti * 2], x1 = As[k][ti * 2 + 1];
            float y0 = Bs[k][tj * 2], y1 = Bs[k][tj * 2 + 1];
            a00 += x0 * y0; a01 += x0 * y1; a10 += x1 * y0; a11 += x1 * y1;
        }
        __syncthreads();
    }
    int i = i0 + ti * 2, j = j0 + tj * 2;
    float av[2][2] = {{a00, a01}, {a10, a11}};
#pragma unroll
    for (int ii = 0; ii < 2; ++ii)
#pragma unroll
        for (int jj = 0; jj < 2; ++jj) {
            int I = i + ii, J = j + jj;
            if (I < NP && J < NP) {
                float v = 0.f;
                if (I < N_ && J < N_) v = adj[I * N_ + J] + 2.f * av[ii][jj];
                S16[I * NP + J] = (_Float16)v;
            }
        }
}

// ---------------- K2: X2[n][bt][c] = relu(inputs @ w_lt^T + b_lt) ------------
__global__ void k_lintrans(const float* __restrict__ in,
                           const float* __restrict__ w,    // (16,3)
                           const float* __restrict__ bias, // (16)
                           float* __restrict__ X2) {
    int idx4 = (blockIdx.x * 256 + threadIdx.x) * 4;
    if (idx4 >= N_ * M_) return;
    int n = idx4 >> 12;
    int r = idx4 & 4095;
    int bt = r >> 4, c0 = r & 15;
    int tok = bt * N_ + n;
    float f0 = in[tok * 3 + 0];
    float f1 = in[tok * 3 + 1];
    float f2 = in[tok * 3 + 2];
    float4 o;
    o.x = fmaxf(bias[c0+0] + f0*w[(c0+0)*3+0] + f1*w[(c0+0)*3+1] + f2*w[(c0+0)*3+2], 0.f);
    o.y = fmaxf(bias[c0+1] + f0*w[(c0+1)*3+0] + f1*w[(c0+1)*3+1] + f2*w[(c0+1)*3+2], 0.f);
    o.z = fmaxf(bias[c0+2] + f0*w[(c0+2)*3+0] + f1*w[(c0+2)*3+1] + f2*w[(c0+2)*3+2], 0.f);
    o.w = fmaxf(bias[c0+3] + f0*w[(c0+3)*3+0] + f1*w[(c0+3)*3+1] + f2*w[(c0+3)*3+2], 0.f);
    *(float4*)&X2[idx4] = o;
}

// ---------------- K3: lfs2 = S @ X2  — f16 MFMA, in-block split-K ------------
// B-fragments built from f32 X2 directly (guarded convert); no transpose buf.
__global__ __launch_bounds__(256) void k_gconv(const _Float16* __restrict__ S16,
                                               const float* __restrict__ X2,
                                               float* __restrict__ lfs2) {
    __shared__ __align__(16) float red[4][16][68];
    int m0 = blockIdx.x * 64;
    int i0 = blockIdx.y * 16;
    int tid = threadIdx.x;
    int w = tid >> 6, l = tid & 63;
    int lr = l & 15, kg = l >> 4;

    int c0 = w * 5;
    int nc = (w == 3) ? 6 : 5;    // 21 chunks of K=16 total (336 = NP)

    f32x4 acc0 = {0.f,0.f,0.f,0.f}, acc1 = acc0, acc2 = acc0, acc3 = acc0;
    const size_t arow = (size_t)(i0 + lr) * NP;
    for (int cc = 0; cc < nc; ++cc) {
        int kb = (c0 + cc) * 16 + kg * 4;
        f16x4 af = *(const f16x4*)&S16[arow + kb];   // pads are zeroed
        f16x4 b0, b1, b2, b3;
#pragma unroll
        for (int j = 0; j < 4; ++j) {
            int k = kb + j;
            float x0 = 0.f, x1 = 0.f, x2 = 0.f, x3 = 0.f;
            if (k < N_) {
                const float* xr = X2 + (size_t)k * M_ + m0;
                x0 = xr[lr]; x1 = xr[16 + lr]; x2 = xr[32 + lr]; x3 = xr[48 + lr];
            }
            b0[j] = (_Float16)x0; b1[j] = (_Float16)x1;
            b2[j] = (_Float16)x2; b3[j] = (_Float16)x3;
        }
        acc0 = MFMA16(af, b0, acc0, 0, 0, 0);
        acc1 = MFMA16(af, b1, acc1, 0, 0, 0);
        acc2 = MFMA16(af, b2, acc2, 0, 0, 0);
        acc3 = MFMA16(af, b3, acc3, 0, 0, 0);
    }
#pragma unroll
    for (int r = 0; r < 4; ++r) {
        red[w][kg * 4 + r][ 0 + lr] = acc0[r];
        red[w][kg * 4 + r][16 + lr] = acc1[r];
        red[w][kg * 4 + r][32 + lr] = acc2[r];
        red[w][kg * 4 + r][48 + lr] = acc3[r];
    }
    __syncthreads();
    int row = tid >> 4, col = (tid & 15) * 4;
    if (i0 + row < N_) {
        float4 p0 = *(const float4*)&red[0][row][col];
        float4 p1 = *(const float4*)&red[1][row][col];
        float4 p2 = *(const float4*)&red[2][row][col];
        float4 p3 = *(const float4*)&red[3][row][col];
        float4 o;
        o.x = (p0.x + p1.x) + (p2.x + p3.x);
        o.y = (p0.y + p1.y) + (p2.y + p3.y);
        o.z = (p0.z + p1.z) + (p2.z + p3.z);
        o.w = (p0.w + p1.w) + (p2.w + p3.w);
        *(float4*)&lfs2[(size_t)(i0 + row) * M_ + m0 + col] = o;
    }
}

// ---------------- K4: MFMA attention, fully fused ----------------------------
__global__ __launch_bounds__(256) void k_attn(
    const float* __restrict__ lfs2, const float* __restrict__ X2,
    const float* __restrict__ wq, const float* __restrict__ bq,
    const float* __restrict__ wk, const float* __restrict__ bk,
    const float* __restrict__ wv, const float* __restrict__ bv,
    const float* __restrict__ wls, const float* __restrict__ bls,
    float* __restrict__ ypre, float* __restrict__ part) {
    __shared__ __align__(16) float Lf[T_ * 20];
    __shared__ __align__(16) float Rs[NH][T_][20];
    __shared__ float lnp[NH][2];
    int bn = blockIdx.x;
    int b = bn / N_, n = bn % N_;
    int tid = threadIdx.x;
    int h = tid >> 6;
    int l = tid & 63;
    int lr = l & 15, kg = l >> 4;

    const float* Lsrc = lfs2 + (size_t)n * M_ + b * (T_ * DH);
    for (int i = tid; i < T_ * DH; i += 256) Lf[(i >> 4) * 20 + (i & 15)] = Lsrc[i];
    __syncthreads();

    f16x4 lff[4];
#pragma unroll
    for (int q = 0; q < 4; ++q) {
        const float4 v = *(const float4*)&Lf[(lr + 16 * q) * 20 + kg * 4];
        f16x4 t; t[0] = (_Float16)v.x; t[1] = (_Float16)v.y; t[2] = (_Float16)v.z; t[3] = (_Float16)v.w;
        lff[q] = t;
    }
    f16x4 wqf, wkf, wvf;
    {
        int base = h * 16 + lr;
#pragma unroll
        for (int j = 0; j < 4; ++j) {
            wqf[j] = (_Float16)wq[(kg * 4 + j) * DD + base];
            wkf[j] = (_Float16)wk[(kg * 4 + j) * DD + base];
            wvf[j] = (_Float16)wv[(kg * 4 + j) * DD + base];
        }
    }
    f32x4 zero = {0.f, 0.f, 0.f, 0.f};

    f16x4 qtf[4], ktf[4], vvf[4];
    {
        float bqr[4], bkr[4];
#pragma unroll
        for (int r = 0; r < 4; ++r) { bqr[r] = bq[h * 16 + kg * 4 + r]; bkr[r] = bk[h * 16 + kg * 4 + r]; }
        float bvc = bv[h * 16 + lr];
#pragma unroll
        for (int q = 0; q < 4; ++q) {
            f32x4 qa = MFMA16(wqf, lff[q], zero, 0, 0, 0);
            f32x4 ka = MFMA16(wkf, lff[q], zero, 0, 0, 0);
            f32x4 va = MFMA16(lff[q], wvf, zero, 0, 0, 0);
#pragma unroll
            for (int r = 0; r < 4; ++r) {
                qtf[q][r] = (_Float16)(fmaxf(qa[r] + bqr[r], 0.f) * 0.25f);
                ktf[q][r] = (_Float16)fmaxf(ka[r] + bkr[r], 0.f);
                vvf[q][r] = (_Float16)fmaxf(va[r] + bvc, 0.f);
            }
        }
    }
    f32x4 st[4][4];
#pragma unroll
    for (int ss = 0; ss < 4; ++ss)
#pragma unroll
        for (int tt = 0; tt < 4; ++tt)
            st[ss][tt] = MFMA16(ktf[ss], qtf[tt], zero, 0, 0, 0);

    f16x4 pf[4][4];
#pragma unroll
    for (int tt = 0; tt < 4; ++tt) {
        int t = tt * 16 + lr;
        float m = -1e30f;
#pragma unroll
        for (int ss = 0; ss < 4; ++ss)
#pragma unroll
            for (int r = 0; r < 4; ++r) m = fmaxf(m, st[ss][tt][r]);
        float e[4][4];
        float sum = 0.f;
#pragma unroll
        for (int ss = 0; ss < 4; ++ss)
#pragma unroll
            for (int r = 0; r < 4; ++r) { float ev = __expf(st[ss][tt][r] - m); e[ss][r] = ev; sum += ev; }
        float inv = 1.f / sum;
#pragma unroll
        for (int ss = 0; ss < 4; ++ss)
#pragma unroll
            for (int r = 0; r < 4; ++r) {
                int s = ss * 16 + kg * 4 + r;
                pf[ss][tt][r] = (s <= t) ? (_Float16)(e[ss][r] * inv) : (_Float16)0.f;
            }
    }
    f16x4 rtf[4];
#pragma unroll
    for (int tt = 0; tt < 4; ++tt) {
        f32x4 acc = zero;
#pragma unroll
        for (int ss = 0; ss < 4; ++ss)
            acc = MFMA16(vvf[ss], pf[ss][tt], acc, 0, 0, 0);
#pragma unroll
        for (int r = 0; r < 4; ++r) rtf[tt][r] = (_Float16)fmaxf(acc[r], 0.f);
    }
    f16x4 wlf;
    {
        const float4 w4 = *(const float4*)&wls[lr * DD + h * 16 + kg * 4];
        wlf[0] = (_Float16)w4.x; wlf[1] = (_Float16)w4.y; wlf[2] = (_Float16)w4.z; wlf[3] = (_Float16)w4.w;
    }
#pragma unroll
    for (int tt = 0; tt < 4; ++tt) {
        f32x4 rp = MFMA16(wlf, rtf[tt], zero, 0, 0, 0);
        float4 o4; o4.x = rp[0]; o4.y = rp[1]; o4.z = rp[2]; o4.w = rp[3];
        *(float4*)&Rs[h][tt * 16 + lr][kg * 4] = o4;
    }
    __syncthreads();

    {
        int t = tid >> 2, o0 = (tid & 3) * 4;
        float4 r0 = *(const float4*)&Rs[0][t][o0];
        float4 r1 = *(const float4*)&Rs[1][t][o0];
        float4 r2 = *(const float4*)&Rs[2][t][o0];
        float4 r3 = *(const float4*)&Rs[3][t][o0];
        const float* Xsrc = X2 + (size_t)n * M_ + b * (T_ * DH);
        float4 xv = *(const float4*)&Xsrc[t * DH + o0];
        float y0 = xv.x + fmaxf(r0.x + r1.x + r2.x + r3.x + bls[o0 + 0], 0.f);
        float y1 = xv.y + fmaxf(r0.y + r1.y + r2.y + r3.y + bls[o0 + 1], 0.f);
        float y2 = xv.z + fmaxf(r0.z + r1.z + r2.z + r3.z + bls[o0 + 2], 0.f);
        float y3 = xv.w + fmaxf(r0.w + r1.w + r2.w + r3.w + bls[o0 + 3], 0.f);
        float4 yv; yv.x = y0; yv.y = y1; yv.z = y2; yv.w = y3;
        *(float4*)&ypre[(size_t)b * 332800 + (size_t)n * 1024 + t * DH + o0] = yv;
        float ls = (y0 + y1) + (y2 + y3);
        float lq = (y0 * y0 + y1 * y1) + (y2 * y2 + y3 * y3);
#pragma unroll
        for (int off = 32; off > 0; off >>= 1) { ls += __shfl_down(ls, off); lq += __shfl_down(lq, off); }
        if (l == 0) { lnp[h][0] = ls; lnp[h][1] = lq; }
    }
    __syncthreads();
    if (tid == 0) {
        part[bn * 2]     = (lnp[0][0] + lnp[1][0]) + (lnp[2][0] + lnp[3][0]);
        part[bn * 2 + 1] = (lnp[0][1] + lnp[1][1]) + (lnp[2][1] + lnp[3][1]);
    }
}

// ---------------- K5: reduce 325 per-block partials -> mu/rsigma per batch ---
__global__ __launch_bounds__(256) void k_lnstat(const float* __restrict__ part, float* __restrict__ stat) {
    __shared__ float ssum[256], ssq[256];
    int b = blockIdx.x, tid = threadIdx.x;
    float s = 0.f, q = 0.f;
    for (int i = tid; i < N_; i += 256) {
        s += part[(b * N_ + i) * 2];
        q += part[(b * N_ + i) * 2 + 1];
    }
    ssum[tid] = s; ssq[tid] = q;
    __syncthreads();
    for (int st = 128; st > 0; st >>= 1) {
        if (tid < st) { ssum[tid] += ssum[tid + st]; ssq[tid] += ssq[tid + st]; }
        __syncthreads();
    }
    if (tid == 0) {
        float mu = ssum[0] / 332800.f;
        float var = ssq[0] / 332800.f - mu * mu;
        stat[b * 2] = mu;
        stat[b * 2 + 1] = rsqrtf(var + 1e-5f);
    }
}

// ---------------- K6: normalize + gamma/beta ---------------------------------
__global__ __launch_bounds__(256) void k_lnapply(const float* __restrict__ y,
                                                 const float* __restrict__ stat,
                                                 const float* __restrict__ gamma,
                                                 const float* __restrict__ beta,
                                                 float* __restrict__ out) {
    int tid = threadIdx.x;
    int idx = blockIdx.x * 256 + tid;
    int b = idx / 332800;
    float mu = stat[b * 2], rs = stat[b * 2 + 1];
    int r = idx - b * 332800;
    int n = r >> 10;
    int rr = r & 1023;
    int t = rr >> 4, c = rr & 15;
    int g = (c * T_ + t) * N_ + n;
    float v = (y[idx] - mu) * rs * gamma[g] + beta[g];
    out[(((size_t)(b * T_ + t) * N_) + n) * DH + c] = v;
}

extern "C" void kernel_launch(void* const* d_in, const int* in_sizes, int n_in,
                              void* d_out, int out_size, void* d_ws, size_t ws_size,
                              hipStream_t stream) {
    const float* in   = (const float*)d_in[0];
    const float* adj  = (const float*)d_in[1];
    const float* w_lt = (const float*)d_in[2];
    const float* b_lt = (const float*)d_in[3];
    const float* wq   = (const float*)d_in[4];
    const float* bq   = (const float*)d_in[5];
    const float* wk   = (const float*)d_in[6];
    const float* bk   = (const float*)d_in[7];
    const float* wv   = (const float*)d_in[8];
    const float* bv   = (const float*)d_in[9];
    const float* wls  = (const float*)d_in[10];
    const float* bls  = (const float*)d_in[11];
    const float* gam  = (const float*)d_in[12];
    const float* bet  = (const float*)d_in[13];
    float* out = (float*)d_out;

    float* ws = (float*)d_ws;
    _Float16* S16 = (_Float16*)ws;                 // 336*336 f16 (pads zeroed by k_support)
    float* X2   = ws + 56576;                      // 1,331,200  (f32 [n][m])
    float* lfs2 = X2 + 1331200;                    // 1,331,200
    float* ypre = lfs2 + 1331200;                  // 1,331,200
    float* part = ypre + 1331200;                  // 2600
    float* stat = part + 2608;                     // 8

    k_support<<<dim3(11, 11), 256, 0, stream>>>(adj, S16);
    k_lintrans<<<(N_ * M_) / 1024, 256, 0, stream>>>(in, w_lt, b_lt, X2);
    k_gconv<<<dim3(64, 21), 256, 0, stream>>>(S16, X2, lfs2);
    k_attn<<<B_ * N_, 256, 0, stream>>>(lfs2, X2, wq, bq, wk, bk, wv, bv, wls, bls, ypre, part);
    k_lnstat<<<4, 256, 0, stream>>>(part, stat);
    k_lnapply<<<(B_ * T_ * N_ * DH) / 256, 256, 0, stream>>>(ypre, stat, gam, bet, out);
}

// Round 11
// 79.964 us; speedup vs baseline: 2.4502x; 1.0329x over previous
//
#include <hip/hip_runtime.h>
#include <hip/hip_bf16.h>

#define B_ 4
#define T_ 64
#define N_ 325
#define NP 336                  // padded graph dim for MFMA gconv
#define F_ 3
#define DH 16
#define DD 64
#define NH 4
#define BT_ 256                 // B*T
#define M_ 4096                 // BT*DH  (GEMM N-dim)

using f16x4 = __attribute__((ext_vector_type(4))) _Float16;
using f32x4 = __attribute__((ext_vector_type(4))) float;
#define MFMA16 __builtin_amdgcn_mfma_f32_16x16x16f16

// ---------------- K1: S16 = f16(adj + 2*adj@adj), pads zeroed in-kernel ------
#define SBM 32
#define SBK 64
__global__ __launch_bounds__(256) void k_support(const float* __restrict__ adj, _Float16* __restrict__ S16) {
    __shared__ float As[SBK][33];
    __shared__ float Bs[SBK][33];
    int j0 = blockIdx.x * SBM, i0 = blockIdx.y * SBM;
    int tid = threadIdx.x;
    int ti = tid & 15, tj = tid >> 4;
    float a00 = 0.f, a01 = 0.f, a10 = 0.f, a11 = 0.f;
    for (int k0 = 0; k0 < N_; k0 += SBK) {
#pragma unroll
        for (int p = 0; p < 8; ++p) {
            int e = tid + p * 256;
            int k = e & 63, ii = e >> 6;
            int row = i0 + ii, col = k0 + k;
            As[k][ii] = (row < N_ && col < N_) ? adj[row * N_ + col] : 0.f;
        }
#pragma unroll
        for (int p = 0; p < 8; ++p) {
            int e = tid + p * 256;
            int jj = e & 31, k = e >> 5;
            int row = k0 + k, col = j0 + jj;
            Bs[k][jj] = (row < N_ && col < N_) ? adj[row * N_ + col] : 0.f;
        }
        __syncthreads();
#pragma unroll
        for (int k = 0; k < SBK; ++k) {
            float x0 = As[k][ti * 2], x1 = As[k][ti * 2 + 1];
            float y0 = Bs[k][tj * 2], y1 = Bs[k][tj * 2 + 1];
            a00 += x0 * y0; a01 += x0 * y1; a10 += x1 * y0; a11 += x1 * y1;
        }
        __syncthreads();
    }
    int i = i0 + ti * 2, j = j0 + tj * 2;
    float av[2][2] = {{a00, a01}, {a10, a11}};
#pragma unroll
    for (int ii = 0; ii < 2; ++ii)
#pragma unroll
        for (int jj = 0; jj < 2; ++jj) {
            int I = i + ii, J = j + jj;
            if (I < NP && J < NP) {
                float v = 0.f;
                if (I < N_ && J < N_) v = adj[I * N_ + J] + 2.f * av[ii][jj];
                S16[I * NP + J] = (_Float16)v;
            }
        }
}

// ---------------- K2: X2[n][bt][c] = relu(inputs @ w_lt^T + b_lt) ------------
__global__ void k_lintrans(const float* __restrict__ in,
                           const float* __restrict__ w,    // (16,3)
                           const float* __restrict__ bias, // (16)
                           float* __restrict__ X2) {
    int idx4 = (blockIdx.x * 256 + threadIdx.x) * 4;
    if (idx4 >= N_ * M_) return;
    int n = idx4 >> 12;
    int r = idx4 & 4095;
    int bt = r >> 4, c0 = r & 15;
    int tok = bt * N_ + n;
    float f0 = in[tok * 3 + 0];
    float f1 = in[tok * 3 + 1];
    float f2 = in[tok * 3 + 2];
    float4 o;
    o.x = fmaxf(bias[c0+0] + f0*w[(c0+0)*3+0] + f1*w[(c0+0)*3+1] + f2*w[(c0+0)*3+2], 0.f);
    o.y = fmaxf(bias[c0+1] + f0*w[(c0+1)*3+0] + f1*w[(c0+1)*3+1] + f2*w[(c0+1)*3+2], 0.f);
    o.z = fmaxf(bias[c0+2] + f0*w[(c0+2)*3+0] + f1*w[(c0+2)*3+1] + f2*w[(c0+2)*3+2], 0.f);
    o.w = fmaxf(bias[c0+3] + f0*w[(c0+3)*3+0] + f1*w[(c0+3)*3+1] + f2*w[(c0+3)*3+2], 0.f);
    *(float4*)&X2[idx4] = o;
}

// ---------------- K3: lfs16 = f16(S @ X2) — f16 MFMA, in-block split-K -------
__global__ __launch_bounds__(256) void k_gconv(const _Float16* __restrict__ S16,
                                               const float* __restrict__ X2,
                                               _Float16* __restrict__ lfs16) {
    __shared__ __align__(16) float red[4][16][68];
    int m0 = blockIdx.x * 64;
    int i0 = blockIdx.y * 16;
    int tid = threadIdx.x;
    int w = tid >> 6, l = tid & 63;
    int lr = l & 15, kg = l >> 4;

    int c0 = w * 5;
    int nc = (w == 3) ? 6 : 5;    // 21 chunks of K=16 total (336 = NP)

    f32x4 acc0 = {0.f,0.f,0.f,0.f}, acc1 = acc0, acc2 = acc0, acc3 = acc0;
    const size_t arow = (size_t)(i0 + lr) * NP;
    for (int cc = 0; cc < nc; ++cc) {
        int kb = (c0 + cc) * 16 + kg * 4;
        f16x4 af = *(const f16x4*)&S16[arow + kb];   // pads are zeroed
        f16x4 b0, b1, b2, b3;
#pragma unroll
        for (int j = 0; j < 4; ++j) {
            int k = kb + j;
            float x0 = 0.f, x1 = 0.f, x2 = 0.f, x3 = 0.f;
            if (k < N_) {
                const float* xr = X2 + (size_t)k * M_ + m0;
                x0 = xr[lr]; x1 = xr[16 + lr]; x2 = xr[32 + lr]; x3 = xr[48 + lr];
            }
            b0[j] = (_Float16)x0; b1[j] = (_Float16)x1;
            b2[j] = (_Float16)x2; b3[j] = (_Float16)x3;
        }
        acc0 = MFMA16(af, b0, acc0, 0, 0, 0);
        acc1 = MFMA16(af, b1, acc1, 0, 0, 0);
        acc2 = MFMA16(af, b2, acc2, 0, 0, 0);
        acc3 = MFMA16(af, b3, acc3, 0, 0, 0);
    }
#pragma unroll
    for (int r = 0; r < 4; ++r) {
        red[w][kg * 4 + r][ 0 + lr] = acc0[r];
        red[w][kg * 4 + r][16 + lr] = acc1[r];
        red[w][kg * 4 + r][32 + lr] = acc2[r];
        red[w][kg * 4 + r][48 + lr] = acc3[r];
    }
    __syncthreads();
    int row = tid >> 4, col = (tid & 15) * 4;
    if (i0 + row < N_) {
        float4 p0 = *(const float4*)&red[0][row][col];
        float4 p1 = *(const float4*)&red[1][row][col];
        float4 p2 = *(const float4*)&red[2][row][col];
        float4 p3 = *(const float4*)&red[3][row][col];
        f16x4 o;
        o[0] = (_Float16)((p0.x + p1.x) + (p2.x + p3.x));
        o[1] = (_Float16)((p0.y + p1.y) + (p2.y + p3.y));
        o[2] = (_Float16)((p0.z + p1.z) + (p2.z + p3.z));
        o[3] = (_Float16)((p0.w + p1.w) + (p2.w + p3.w));
        *(f16x4*)&lfs16[(size_t)(i0 + row) * M_ + m0 + col] = o;
    }
}

// ---------------- K4: MFMA attention — direct f16 fragment loads -------------
__global__ __launch_bounds__(256) void k_attn(
    const _Float16* __restrict__ lfs16, const float* __restrict__ in,
    const float* __restrict__ wlt, const float* __restrict__ blt,
    const float* __restrict__ wq, const float* __restrict__ bq,
    const float* __restrict__ wk, const float* __restrict__ bk,
    const float* __restrict__ wv, const float* __restrict__ bv,
    const float* __restrict__ wls, const float* __restrict__ bls,
    float* __restrict__ ypre, float* __restrict__ part) {
    __shared__ __align__(16) float Rs[NH][T_][20];
    __shared__ float lnp[NH][2];
    int bn = blockIdx.x;
    int b = bn / N_, n = bn % N_;
    int tid = threadIdx.x;
    int h = tid >> 6;
    int l = tid & 63;
    int lr = l & 15, kg = l >> 4;

    // direct fragment loads: contiguous 512B per q across the wave
    const _Float16* Lsrc = lfs16 + (size_t)n * M_ + b * (T_ * DH);
    f16x4 lff[4];
#pragma unroll
    for (int q = 0; q < 4; ++q)
        lff[q] = *(const f16x4*)&Lsrc[(lr + 16 * q) * DH + kg * 4];

    f16x4 wqf, wkf, wvf;
    {
        int base = h * 16 + lr;
#pragma unroll
        for (int j = 0; j < 4; ++j) {
            wqf[j] = (_Float16)wq[(kg * 4 + j) * DD + base];
            wkf[j] = (_Float16)wk[(kg * 4 + j) * DD + base];
            wvf[j] = (_Float16)wv[(kg * 4 + j) * DD + base];
        }
    }
    f32x4 zero = {0.f, 0.f, 0.f, 0.f};

    f16x4 qtf[4], ktf[4], vvf[4];
    {
        float bqr[4], bkr[4];
#pragma unroll
        for (int r = 0; r < 4; ++r) { bqr[r] = bq[h * 16 + kg * 4 + r]; bkr[r] = bk[h * 16 + kg * 4 + r]; }
        float bvc = bv[h * 16 + lr];
#pragma unroll
        for (int q = 0; q < 4; ++q) {
            f32x4 qa = MFMA16(wqf, lff[q], zero, 0, 0, 0);
            f32x4 ka = MFMA16(wkf, lff[q], zero, 0, 0, 0);
            f32x4 va = MFMA16(lff[q], wvf, zero, 0, 0, 0);
#pragma unroll
            for (int r = 0; r < 4; ++r) {
                qtf[q][r] = (_Float16)(fmaxf(qa[r] + bqr[r], 0.f) * 0.25f);
                ktf[q][r] = (_Float16)fmaxf(ka[r] + bkr[r], 0.f);
                vvf[q][r] = (_Float16)fmaxf(va[r] + bvc, 0.f);
            }
        }
    }
    f32x4 st[4][4];
#pragma unroll
    for (int ss = 0; ss < 4; ++ss)
#pragma unroll
        for (int tt = 0; tt < 4; ++tt)
            st[ss][tt] = MFMA16(ktf[ss], qtf[tt], zero, 0, 0, 0);

    f16x4 pf[4][4];
#pragma unroll
    for (int tt = 0; tt < 4; ++tt) {
        int t = tt * 16 + lr;
        float m = -1e30f;
#pragma unroll
        for (int ss = 0; ss < 4; ++ss)
#pragma unroll
            for (int r = 0; r < 4; ++r) m = fmaxf(m, st[ss][tt][r]);
        float e[4][4];
        float sum = 0.f;
#pragma unroll
        for (int ss = 0; ss < 4; ++ss)
#pragma unroll
            for (int r = 0; r < 4; ++r) { float ev = __expf(st[ss][tt][r] - m); e[ss][r] = ev; sum += ev; }
        float inv = 1.f / sum;
#pragma unroll
        for (int ss = 0; ss < 4; ++ss)
#pragma unroll
            for (int r = 0; r < 4; ++r) {
                int s = ss * 16 + kg * 4 + r;
                pf[ss][tt][r] = (s <= t) ? (_Float16)(e[ss][r] * inv) : (_Float16)0.f;
            }
    }
    f16x4 rtf[4];
#pragma unroll
    for (int tt = 0; tt < 4; ++tt) {
        f32x4 acc = zero;
#pragma unroll
        for (int ss = 0; ss < 4; ++ss)
            acc = MFMA16(vvf[ss], pf[ss][tt], acc, 0, 0, 0);
#pragma unroll
        for (int r = 0; r < 4; ++r) rtf[tt][r] = (_Float16)fmaxf(acc[r], 0.f);
    }
    f16x4 wlf;
    {
        const float4 w4 = *(const float4*)&wls[lr * DD + h * 16 + kg * 4];
        wlf[0] = (_Float16)w4.x; wlf[1] = (_Float16)w4.y; wlf[2] = (_Float16)w4.z; wlf[3] = (_Float16)w4.w;
    }
#pragma unroll
    for (int tt = 0; tt < 4; ++tt) {
        f32x4 rp = MFMA16(wlf, rtf[tt], zero, 0, 0, 0);
        float4 o4; o4.x = rp[0]; o4.y = rp[1]; o4.z = rp[2]; o4.w = rp[3];
        *(float4*)&Rs[h][tt * 16 + lr][kg * 4] = o4;
    }
    __syncthreads();

    {
        int t = tid >> 2, o0 = (tid & 3) * 4;
        float4 r0 = *(const float4*)&Rs[0][t][o0];
        float4 r1 = *(const float4*)&Rs[1][t][o0];
        float4 r2 = *(const float4*)&Rs[2][t][o0];
        float4 r3 = *(const float4*)&Rs[3][t][o0];
        // recompute residual X = relu(w_lt @ inputs + b_lt) for (b,t,n)
        int tok = ((b * T_ + t) * N_ + n) * 3;
        float f0 = in[tok], f1 = in[tok + 1], f2 = in[tok + 2];
        float xv[4];
#pragma unroll
        for (int i = 0; i < 4; ++i) {
            int c = o0 + i;
            xv[i] = fmaxf(blt[c] + f0 * wlt[c * 3 + 0] + f1 * wlt[c * 3 + 1] + f2 * wlt[c * 3 + 2], 0.f);
        }
        float y0 = xv[0] + fmaxf(r0.x + r1.x + r2.x + r3.x + bls[o0 + 0], 0.f);
        float y1 = xv[1] + fmaxf(r0.y + r1.y + r2.y + r3.y + bls[o0 + 1], 0.f);
        float y2 = xv[2] + fmaxf(r0.z + r1.z + r2.z + r3.z + bls[o0 + 2], 0.f);
        float y3 = xv[3] + fmaxf(r0.w + r1.w + r2.w + r3.w + bls[o0 + 3], 0.f);
        float4 yv; yv.x = y0; yv.y = y1; yv.z = y2; yv.w = y3;
        *(float4*)&ypre[(size_t)b * 332800 + (size_t)n * 1024 + t * DH + o0] = yv;
        float ls = (y0 + y1) + (y2 + y3);
        float lq = (y0 * y0 + y1 * y1) + (y2 * y2 + y3 * y3);
#pragma unroll
        for (int off = 32; off > 0; off >>= 1) { ls += __shfl_down(ls, off); lq += __shfl_down(lq, off); }
        if (l == 0) { lnp[h][0] = ls; lnp[h][1] = lq; }
    }
    __syncthreads();
    if (tid == 0) {
        part[bn * 2]     = (lnp[0][0] + lnp[1][0]) + (lnp[2][0] + lnp[3][0]);
        part[bn * 2 + 1] = (lnp[0][1] + lnp[1][1]) + (lnp[2][1] + lnp[3][1]);
    }
}

// ---------------- K5: reduce 1300 per-block partials -> mu/rsigma per batch --
__global__ __launch_bounds__(256) void k_lnstat(const float* __restrict__ part, float* __restrict__ stat) {
    __shared__ float ssum[256], ssq[256];
    int b = blockIdx.x, tid = threadIdx.x;
    float s = 0.f, q = 0.f;
    for (int i = tid; i < N_; i += 256) {
        s += part[(b * N_ + i) * 2];
        q += part[(b * N_ + i) * 2 + 1];
    }
    ssum[tid] = s; ssq[tid] = q;
    __syncthreads();
    for (int st = 128; st > 0; st >>= 1) {
        if (tid < st) { ssum[tid] += ssum[tid + st]; ssq[tid] += ssq[tid + st]; }
        __syncthreads();
    }
    if (tid == 0) {
        float mu = ssum[0] / 332800.f;
        float var = ssq[0] / 332800.f - mu * mu;
        stat[b * 2] = mu;
        stat[b * 2 + 1] = rsqrtf(var + 1e-5f);
    }
}

// ---------------- K6: normalize + gamma/beta (4 elems/thread) ----------------
__global__ __launch_bounds__(256) void k_lnapply(const float* __restrict__ y,
                                                 const float* __restrict__ stat,
                                                 const float* __restrict__ gamma,
                                                 const float* __restrict__ beta,
                                                 float* __restrict__ out) {
    int idx4 = (blockIdx.x * 256 + threadIdx.x) * 4;
    int b = idx4 / 332800;
    float mu = stat[b * 2], rs = stat[b * 2 + 1];
    int r = idx4 - b * 332800;
    int n = r >> 10;
    int rr = r & 1023;
    int t = rr >> 4, c0 = rr & 15;
    float4 yv = *(const float4*)&y[idx4];
    float4 o;
    int g0 = ((c0 + 0) * T_ + t) * N_ + n;
    int g1 = ((c0 + 1) * T_ + t) * N_ + n;
    int g2 = ((c0 + 2) * T_ + t) * N_ + n;
    int g3 = ((c0 + 3) * T_ + t) * N_ + n;
    o.x = (yv.x - mu) * rs * gamma[g0] + beta[g0];
    o.y = (yv.y - mu) * rs * gamma[g1] + beta[g1];
    o.z = (yv.z - mu) * rs * gamma[g2] + beta[g2];
    o.w = (yv.w - mu) * rs * gamma[g3] + beta[g3];
    *(float4*)&out[(((size_t)(b * T_ + t) * N_) + n) * DH + c0] = o;
}

extern "C" void kernel_launch(void* const* d_in, const int* in_sizes, int n_in,
                              void* d_out, int out_size, void* d_ws, size_t ws_size,
                              hipStream_t stream) {
    const float* in   = (const float*)d_in[0];
    const float* adj  = (const float*)d_in[1];
    const float* w_lt = (const float*)d_in[2];
    const float* b_lt = (const float*)d_in[3];
    const float* wq   = (const float*)d_in[4];
    const float* bq   = (const float*)d_in[5];
    const float* wk   = (const float*)d_in[6];
    const float* bk   = (const float*)d_in[7];
    const float* wv   = (const float*)d_in[8];
    const float* bv   = (const float*)d_in[9];
    const float* wls  = (const float*)d_in[10];
    const float* bls  = (const float*)d_in[11];
    const float* gam  = (const float*)d_in[12];
    const float* bet  = (const float*)d_in[13];
    float* out = (float*)d_out;

    float* ws = (float*)d_ws;
    _Float16* S16 = (_Float16*)ws;                 // 336*336 f16 (pads zeroed by k_support)
    float* X2   = ws + 56576;                      // 1,331,200 f32 [n][m]
    _Float16* lfs16 = (_Float16*)(X2 + 1331200);   // 1,331,200 f16 = 665,600 f32 slots
    float* ypre = X2 + 1331200 + 665600;           // 1,331,200
    float* part = ypre + 1331200;                  // 2600
    float* stat = part + 2608;                     // 8

    k_support<<<dim3(11, 11), 256, 0, stream>>>(adj, S16);
    k_lintrans<<<(N_ * M_) / 1024, 256, 0, stream>>>(in, w_lt, b_lt, X2);
    k_gconv<<<dim3(64, 21), 256, 0, stream>>>(S16, X2, lfs16);
    k_attn<<<B_ * N_, 256, 0, stream>>>(lfs16, in, w_lt, b_lt, wq, bq, wk, bk, wv, bv, wls, bls, ypre, part);
    k_lnstat<<<4, 256, 0, stream>>>(part, stat);
    k_lnapply<<<(B_ * T_ * N_ * DH) / 1024, 256, 0, stream>>>(ypre, stat, gam, bet, out);
}

// Round 12
// 76.727 us; speedup vs baseline: 2.5536x; 1.0422x over previous
//
#include <hip/hip_runtime.h>
#include <hip/hip_bf16.h>

#define B_ 4
#define T_ 64
#define N_ 325
#define NP 336                  // padded graph dim for MFMA gconv
#define F_ 3
#define DH 16
#define DD 64
#define NH 4
#define BT_ 256                 // B*T
#define M_ 4096                 // BT*DH  (GEMM N-dim)

using f16x4 = __attribute__((ext_vector_type(4))) _Float16;
using f32x4 = __attribute__((ext_vector_type(4))) float;
#define MFMA16 __builtin_amdgcn_mfma_f32_16x16x16f16

// ---------------- K1: S16 = f16(adj + 2*adj@adj), pads zeroed in-kernel ------
#define SBM 32
#define SBK 64
__global__ __launch_bounds__(256) void k_support(const float* __restrict__ adj, _Float16* __restrict__ S16) {
    __shared__ float As[SBK][33];
    __shared__ float Bs[SBK][33];
    int j0 = blockIdx.x * SBM, i0 = blockIdx.y * SBM;
    int tid = threadIdx.x;
    int ti = tid & 15, tj = tid >> 4;
    float a00 = 0.f, a01 = 0.f, a10 = 0.f, a11 = 0.f;
    for (int k0 = 0; k0 < N_; k0 += SBK) {
#pragma unroll
        for (int p = 0; p < 8; ++p) {
            int e = tid + p * 256;
            int k = e & 63, ii = e >> 6;
            int row = i0 + ii, col = k0 + k;
            As[k][ii] = (row < N_ && col < N_) ? adj[row * N_ + col] : 0.f;
        }
#pragma unroll
        for (int p = 0; p < 8; ++p) {
            int e = tid + p * 256;
            int jj = e & 31, k = e >> 5;
            int row = k0 + k, col = j0 + jj;
            Bs[k][jj] = (row < N_ && col < N_) ? adj[row * N_ + col] : 0.f;
        }
        __syncthreads();
#pragma unroll
        for (int k = 0; k < SBK; ++k) {
            float x0 = As[k][ti * 2], x1 = As[k][ti * 2 + 1];
            float y0 = Bs[k][tj * 2], y1 = Bs[k][tj * 2 + 1];
            a00 += x0 * y0; a01 += x0 * y1; a10 += x1 * y0; a11 += x1 * y1;
        }
        __syncthreads();
    }
    int i = i0 + ti * 2, j = j0 + tj * 2;
    float av[2][2] = {{a00, a01}, {a10, a11}};
#pragma unroll
    for (int ii = 0; ii < 2; ++ii)
#pragma unroll
        for (int jj = 0; jj < 2; ++jj) {
            int I = i + ii, J = j + jj;
            if (I < NP && J < NP) {
                float v = 0.f;
                if (I < N_ && J < N_) v = adj[I * N_ + J] + 2.f * av[ii][jj];
                S16[I * NP + J] = (_Float16)v;
            }
        }
}

// ---------------- K2: X16[n][bt][c] = f16(relu(inputs @ w_lt^T + b_lt)) ------
__global__ void k_lintrans(const float* __restrict__ in,
                           const float* __restrict__ w,    // (16,3)
                           const float* __restrict__ bias, // (16)
                           _Float16* __restrict__ X16) {
    int idx4 = (blockIdx.x * 256 + threadIdx.x) * 4;
    if (idx4 >= N_ * M_) return;
    int n = idx4 >> 12;
    int r = idx4 & 4095;
    int bt = r >> 4, c0 = r & 15;
    int tok = bt * N_ + n;
    float f0 = in[tok * 3 + 0];
    float f1 = in[tok * 3 + 1];
    float f2 = in[tok * 3 + 2];
    f16x4 o;
    o[0] = (_Float16)fmaxf(bias[c0+0] + f0*w[(c0+0)*3+0] + f1*w[(c0+0)*3+1] + f2*w[(c0+0)*3+2], 0.f);
    o[1] = (_Float16)fmaxf(bias[c0+1] + f0*w[(c0+1)*3+0] + f1*w[(c0+1)*3+1] + f2*w[(c0+1)*3+2], 0.f);
    o[2] = (_Float16)fmaxf(bias[c0+2] + f0*w[(c0+2)*3+0] + f1*w[(c0+2)*3+1] + f2*w[(c0+2)*3+2], 0.f);
    o[3] = (_Float16)fmaxf(bias[c0+3] + f0*w[(c0+3)*3+0] + f1*w[(c0+3)*3+1] + f2*w[(c0+3)*3+2], 0.f);
    *(f16x4*)&X16[idx4] = o;
}

// ---------------- K3: lfs16 = f16(S @ X) — f16 MFMA, in-block split-K --------
__global__ __launch_bounds__(256) void k_gconv(const _Float16* __restrict__ S16,
                                               const _Float16* __restrict__ X16,
                                               _Float16* __restrict__ lfs16) {
    __shared__ __align__(16) float red[4][16][68];
    int m0 = blockIdx.x * 64;
    int i0 = blockIdx.y * 16;
    int tid = threadIdx.x;
    int w = tid >> 6, l = tid & 63;
    int lr = l & 15, kg = l >> 4;

    int c0 = w * 5;
    int nc = (w == 3) ? 6 : 5;    // 21 chunks of K=16 total (336 = NP)

    f32x4 acc0 = {0.f,0.f,0.f,0.f}, acc1 = acc0, acc2 = acc0, acc3 = acc0;
    const size_t arow = (size_t)(i0 + lr) * NP;
    for (int cc = 0; cc < nc; ++cc) {
        int kb = (c0 + cc) * 16 + kg * 4;
        f16x4 af = *(const f16x4*)&S16[arow + kb];   // pads are zeroed
        f16x4 b0, b1, b2, b3;
#pragma unroll
        for (int j = 0; j < 4; ++j) {
            int k = kb + j;
            _Float16 x0 = (_Float16)0.f, x1 = x0, x2 = x0, x3 = x0;
            if (k < N_) {
                const _Float16* xr = X16 + (size_t)k * M_ + m0;
                x0 = xr[lr]; x1 = xr[16 + lr]; x2 = xr[32 + lr]; x3 = xr[48 + lr];
            }
            b0[j] = x0; b1[j] = x1; b2[j] = x2; b3[j] = x3;
        }
        acc0 = MFMA16(af, b0, acc0, 0, 0, 0);
        acc1 = MFMA16(af, b1, acc1, 0, 0, 0);
        acc2 = MFMA16(af, b2, acc2, 0, 0, 0);
        acc3 = MFMA16(af, b3, acc3, 0, 0, 0);
    }
#pragma unroll
    for (int r = 0; r < 4; ++r) {
        red[w][kg * 4 + r][ 0 + lr] = acc0[r];
        red[w][kg * 4 + r][16 + lr] = acc1[r];
        red[w][kg * 4 + r][32 + lr] = acc2[r];
        red[w][kg * 4 + r][48 + lr] = acc3[r];
    }
    __syncthreads();
    int row = tid >> 4, col = (tid & 15) * 4;
    if (i0 + row < N_) {
        float4 p0 = *(const float4*)&red[0][row][col];
        float4 p1 = *(const float4*)&red[1][row][col];
        float4 p2 = *(const float4*)&red[2][row][col];
        float4 p3 = *(const float4*)&red[3][row][col];
        f16x4 o;
        o[0] = (_Float16)((p0.x + p1.x) + (p2.x + p3.x));
        o[1] = (_Float16)((p0.y + p1.y) + (p2.y + p3.y));
        o[2] = (_Float16)((p0.z + p1.z) + (p2.z + p3.z));
        o[3] = (_Float16)((p0.w + p1.w) + (p2.w + p3.w));
        *(f16x4*)&lfs16[(size_t)(i0 + row) * M_ + m0 + col] = o;
    }
}

// ---------------- K4: MFMA attention — correct cross-lane softmax ------------
__global__ __launch_bounds__(256) void k_attn(
    const _Float16* __restrict__ lfs16, const float* __restrict__ in,
    const float* __restrict__ wlt, const float* __restrict__ blt,
    const float* __restrict__ wq, const float* __restrict__ bq,
    const float* __restrict__ wk, const float* __restrict__ bk,
    const float* __restrict__ wv, const float* __restrict__ bv,
    const float* __restrict__ wls, const float* __restrict__ bls,
    float* __restrict__ ypre, float* __restrict__ part) {
    __shared__ __align__(16) float Rs[NH][T_][20];
    __shared__ float lnp[NH][2];
    int bn = blockIdx.x;
    int b = bn / N_, n = bn % N_;
    int tid = threadIdx.x;
    int h = tid >> 6;
    int l = tid & 63;
    int lr = l & 15, kg = l >> 4;

    // direct fragment loads: contiguous 512B per q across the wave
    const _Float16* Lsrc = lfs16 + (size_t)n * M_ + b * (T_ * DH);
    f16x4 lff[4];
#pragma unroll
    for (int q = 0; q < 4; ++q)
        lff[q] = *(const f16x4*)&Lsrc[(lr + 16 * q) * DH + kg * 4];

    f16x4 wqf, wkf, wvf;
    {
        int base = h * 16 + lr;
#pragma unroll
        for (int j = 0; j < 4; ++j) {
            wqf[j] = (_Float16)wq[(kg * 4 + j) * DD + base];
            wkf[j] = (_Float16)wk[(kg * 4 + j) * DD + base];
            wvf[j] = (_Float16)wv[(kg * 4 + j) * DD + base];
        }
    }
    f32x4 zero = {0.f, 0.f, 0.f, 0.f};

    f16x4 qtf[4], ktf[4], vvf[4];
    {
        float bqr[4], bkr[4];
#pragma unroll
        for (int r = 0; r < 4; ++r) { bqr[r] = bq[h * 16 + kg * 4 + r]; bkr[r] = bk[h * 16 + kg * 4 + r]; }
        float bvc = bv[h * 16 + lr];
#pragma unroll
        for (int q = 0; q < 4; ++q) {
            f32x4 qa = MFMA16(wqf, lff[q], zero, 0, 0, 0);
            f32x4 ka = MFMA16(wkf, lff[q], zero, 0, 0, 0);
            f32x4 va = MFMA16(lff[q], wvf, zero, 0, 0, 0);
#pragma unroll
            for (int r = 0; r < 4; ++r) {
                qtf[q][r] = (_Float16)(fmaxf(qa[r] + bqr[r], 0.f) * 0.25f);
                ktf[q][r] = (_Float16)fmaxf(ka[r] + bkr[r], 0.f);
                vvf[q][r] = (_Float16)fmaxf(va[r] + bvc, 0.f);
            }
        }
    }
    // st[ss][tt][r] = S[t=16tt+lr][s=16ss+kg*4+r]
    f32x4 st[4][4];
#pragma unroll
    for (int ss = 0; ss < 4; ++ss)
#pragma unroll
        for (int tt = 0; tt < 4; ++tt)
            st[ss][tt] = MFMA16(ktf[ss], qtf[tt], zero, 0, 0, 0);

    // softmax over s: each lane holds 16 of 64 values; lanes {l, l^16, l^32}
    // (same lr, different kg) hold the complement -> shfl_xor reduce.
    f16x4 pf[4][4];
#pragma unroll
    for (int tt = 0; tt < 4; ++tt) {
        int t = tt * 16 + lr;
        float m = -1e30f;
#pragma unroll
        for (int ss = 0; ss < 4; ++ss)
#pragma unroll
            for (int r = 0; r < 4; ++r) m = fmaxf(m, st[ss][tt][r]);
        m = fmaxf(m, __shfl_xor(m, 16));
        m = fmaxf(m, __shfl_xor(m, 32));
        float e[4][4];
        float sum = 0.f;
#pragma unroll
        for (int ss = 0; ss < 4; ++ss)
#pragma unroll
            for (int r = 0; r < 4; ++r) { float ev = __expf(st[ss][tt][r] - m); e[ss][r] = ev; sum += ev; }
        sum += __shfl_xor(sum, 16);
        sum += __shfl_xor(sum, 32);
        float inv = 1.f / sum;
#pragma unroll
        for (int ss = 0; ss < 4; ++ss)
#pragma unroll
            for (int r = 0; r < 4; ++r) {
                int s = ss * 16 + kg * 4 + r;
                pf[ss][tt][r] = (s <= t) ? (_Float16)(e[ss][r] * inv) : (_Float16)0.f;
            }
    }
    f16x4 rtf[4];
#pragma unroll
    for (int tt = 0; tt < 4; ++tt) {
        f32x4 acc = zero;
#pragma unroll
        for (int ss = 0; ss < 4; ++ss)
            acc = MFMA16(vvf[ss], pf[ss][tt], acc, 0, 0, 0);
#pragma unroll
        for (int r = 0; r < 4; ++r) rtf[tt][r] = (_Float16)fmaxf(acc[r], 0.f);
    }
    f16x4 wlf;
    {
        const float4 w4 = *(const float4*)&wls[lr * DD + h * 16 + kg * 4];
        wlf[0] = (_Float16)w4.x; wlf[1] = (_Float16)w4.y; wlf[2] = (_Float16)w4.z; wlf[3] = (_Float16)w4.w;
    }
#pragma unroll
    for (int tt = 0; tt < 4; ++tt) {
        f32x4 rp = MFMA16(wlf, rtf[tt], zero, 0, 0, 0);
        float4 o4; o4.x = rp[0]; o4.y = rp[1]; o4.z = rp[2]; o4.w = rp[3];
        *(float4*)&Rs[h][tt * 16 + lr][kg * 4] = o4;
    }
    __syncthreads();

    {
        int t = tid >> 2, o0 = (tid & 3) * 4;
        float4 r0 = *(const float4*)&Rs[0][t][o0];
        float4 r1 = *(const float4*)&Rs[1][t][o0];
        float4 r2 = *(const float4*)&Rs[2][t][o0];
        float4 r3 = *(const float4*)&Rs[3][t][o0];
        // recompute residual X = relu(w_lt @ inputs + b_lt) for (b,t,n)
        int tok = ((b * T_ + t) * N_ + n) * 3;
        float f0 = in[tok], f1 = in[tok + 1], f2 = in[tok + 2];
        float xv[4];
#pragma unroll
        for (int i = 0; i < 4; ++i) {
            int c = o0 + i;
            xv[i] = fmaxf(blt[c] + f0 * wlt[c * 3 + 0] + f1 * wlt[c * 3 + 1] + f2 * wlt[c * 3 + 2], 0.f);
        }
        float y0 = xv[0] + fmaxf(r0.x + r1.x + r2.x + r3.x + bls[o0 + 0], 0.f);
        float y1 = xv[1] + fmaxf(r0.y + r1.y + r2.y + r3.y + bls[o0 + 1], 0.f);
        float y2 = xv[2] + fmaxf(r0.z + r1.z + r2.z + r3.z + bls[o0 + 2], 0.f);
        float y3 = xv[3] + fmaxf(r0.w + r1.w + r2.w + r3.w + bls[o0 + 3], 0.f);
        float4 yv; yv.x = y0; yv.y = y1; yv.z = y2; yv.w = y3;
        *(float4*)&ypre[(size_t)b * 332800 + (size_t)n * 1024 + t * DH + o0] = yv;
        float ls = (y0 + y1) + (y2 + y3);
        float lq = (y0 * y0 + y1 * y1) + (y2 * y2 + y3 * y3);
#pragma unroll
        for (int off = 32; off > 0; off >>= 1) { ls += __shfl_down(ls, off); lq += __shfl_down(lq, off); }
        if (l == 0) { lnp[h][0] = ls; lnp[h][1] = lq; }
    }
    __syncthreads();
    if (tid == 0) {
        part[bn * 2]     = (lnp[0][0] + lnp[1][0]) + (lnp[2][0] + lnp[3][0]);
        part[bn * 2 + 1] = (lnp[0][1] + lnp[1][1]) + (lnp[2][1] + lnp[3][1]);
    }
}

// ---------------- K5: reduce per-(b,n) partials -> mu/rsigma per batch -------
__global__ __launch_bounds__(256) void k_lnstat(const float* __restrict__ part, float* __restrict__ stat) {
    __shared__ float ssum[256], ssq[256];
    int b = blockIdx.x, tid = threadIdx.x;
    float s = 0.f, q = 0.f;
    for (int i = tid; i < N_; i += 256) {
        s += part[(b * N_ + i) * 2];
        q += part[(b * N_ + i) * 2 + 1];
    }
    ssum[tid] = s; ssq[tid] = q;
    __syncthreads();
    for (int st = 128; st > 0; st >>= 1) {
        if (tid < st) { ssum[tid] += ssum[tid + st]; ssq[tid] += ssq[tid + st]; }
        __syncthreads();
    }
    if (tid == 0) {
        float mu = ssum[0] / 332800.f;
        float var = ssq[0] / 332800.f - mu * mu;
        stat[b * 2] = mu;
        stat[b * 2 + 1] = rsqrtf(var + 1e-5f);
    }
}

// ---------------- K6: normalize + gamma/beta (4 elems/thread) ----------------
__global__ __launch_bounds__(256) void k_lnapply(const float* __restrict__ y,
                                                 const float* __restrict__ stat,
                                                 const float* __restrict__ gamma,
                                                 const float* __restrict__ beta,
                                                 float* __restrict__ out) {
    int idx4 = (blockIdx.x * 256 + threadIdx.x) * 4;
    int b = idx4 / 332800;
    float mu = stat[b * 2], rs = stat[b * 2 + 1];
    int r = idx4 - b * 332800;
    int n = r >> 10;
    int rr = r & 1023;
    int t = rr >> 4, c0 = rr & 15;
    float4 yv = *(const float4*)&y[idx4];
    float4 o;
    int g0 = ((c0 + 0) * T_ + t) * N_ + n;
    int g1 = ((c0 + 1) * T_ + t) * N_ + n;
    int g2 = ((c0 + 2) * T_ + t) * N_ + n;
    int g3 = ((c0 + 3) * T_ + t) * N_ + n;
    o.x = (yv.x - mu) * rs * gamma[g0] + beta[g0];
    o.y = (yv.y - mu) * rs * gamma[g1] + beta[g1];
    o.z = (yv.z - mu) * rs * gamma[g2] + beta[g2];
    o.w = (yv.w - mu) * rs * gamma[g3] + beta[g3];
    *(float4*)&out[(((size_t)(b * T_ + t) * N_) + n) * DH + c0] = o;
}

extern "C" void kernel_launch(void* const* d_in, const int* in_sizes, int n_in,
                              void* d_out, int out_size, void* d_ws, size_t ws_size,
                              hipStream_t stream) {
    const float* in   = (const float*)d_in[0];
    const float* adj  = (const float*)d_in[1];
    const float* w_lt = (const float*)d_in[2];
    const float* b_lt = (const float*)d_in[3];
    const float* wq   = (const float*)d_in[4];
    const float* bq   = (const float*)d_in[5];
    const float* wk   = (const float*)d_in[6];
    const float* bk   = (const float*)d_in[7];
    const float* wv   = (const float*)d_in[8];
    const float* bv   = (const float*)d_in[9];
    const float* wls  = (const float*)d_in[10];
    const float* bls  = (const float*)d_in[11];
    const float* gam  = (const float*)d_in[12];
    const float* bet  = (const float*)d_in[13];
    float* out = (float*)d_out;

    float* ws = (float*)d_ws;
    _Float16* S16 = (_Float16*)ws;                 // 336*336 f16 (pads zeroed by k_support)
    _Float16* X16 = (_Float16*)(ws + 56576);       // 1,331,200 f16 = 665,600 f32 slots
    _Float16* lfs16 = (_Float16*)(ws + 56576 + 665600);   // 1,331,200 f16
    float* ypre = ws + 56576 + 665600 + 665600;    // 1,331,200 f32
    float* part = ypre + 1331200;                  // 2600
    float* stat = part + 2608;                     // 8

    k_support<<<dim3(11, 11), 256, 0, stream>>>(adj, S16);
    k_lintrans<<<(N_ * M_) / 1024, 256, 0, stream>>>(in, w_lt, b_lt, X16);
    k_gconv<<<dim3(64, 21), 256, 0, stream>>>(S16, X16, lfs16);
    k_attn<<<B_ * N_, 256, 0, stream>>>(lfs16, in, w_lt, b_lt, wq, bq, wk, bk, wv, bv, wls, bls, ypre, part);
    k_lnstat<<<4, 256, 0, stream>>>(part, stat);
    k_lnapply<<<(B_ * T_ * N_ * DH) / 1024, 256, 0, stream>>>(ypre, stat, gam, bet, out);
}

// Round 13
// 71.770 us; speedup vs baseline: 2.7299x; 1.0691x over previous
//
#include <hip/hip_runtime.h>
#include <hip/hip_bf16.h>

#define B_ 4
#define T_ 64
#define N_ 325
#define NP 336                  // padded graph dim for MFMA
#define F_ 3
#define DH 16
#define DD 64
#define NH 4
#define BT_ 256                 // B*T
#define M_ 4096                 // BT*DH  (GEMM N-dim)

using f16x4 = __attribute__((ext_vector_type(4))) _Float16;
using f32x4 = __attribute__((ext_vector_type(4))) float;
#define MFMA16 __builtin_amdgcn_mfma_f32_16x16x16f16

// ---------------- K1: S16 = f16(adj + 2*adj@adj) — MFMA, split-K -------------
__global__ __launch_bounds__(256) void k_support(const float* __restrict__ adj, _Float16* __restrict__ S16) {
    __shared__ __align__(16) float red[4][16][68];
    int j0 = blockIdx.x * 64;
    int i0 = blockIdx.y * 16;
    int tid = threadIdx.x;
    int w = tid >> 6, l = tid & 63;
    int lr = l & 15, kg = l >> 4;
    int c0 = w * 5;
    int nc = (w == 3) ? 6 : 5;    // 21 K-chunks of 16 over NP=336

    f32x4 acc0 = {0.f,0.f,0.f,0.f}, acc1 = acc0, acc2 = acc0, acc3 = acc0;
    int I = i0 + lr;
    for (int cc = 0; cc < nc; ++cc) {
        int kb = (c0 + cc) * 16 + kg * 4;
        f16x4 af, b0, b1, b2, b3;
#pragma unroll
        for (int j = 0; j < 4; ++j) {
            int k = kb + j;
            af[j] = (I < N_ && k < N_) ? (_Float16)adj[I * N_ + k] : (_Float16)0.f;
            _Float16 x0 = (_Float16)0.f, x1 = x0, x2 = x0, x3 = x0;
            if (k < N_) {
                const float* ar = adj + (size_t)k * N_;
                int m0 = j0 + lr;
                if (m0 < N_)      x0 = (_Float16)ar[m0];
                if (m0 + 16 < N_) x1 = (_Float16)ar[m0 + 16];
                if (m0 + 32 < N_) x2 = (_Float16)ar[m0 + 32];
                if (m0 + 48 < N_) x3 = (_Float16)ar[m0 + 48];
            }
            b0[j] = x0; b1[j] = x1; b2[j] = x2; b3[j] = x3;
        }
        acc0 = MFMA16(af, b0, acc0, 0, 0, 0);
        acc1 = MFMA16(af, b1, acc1, 0, 0, 0);
        acc2 = MFMA16(af, b2, acc2, 0, 0, 0);
        acc3 = MFMA16(af, b3, acc3, 0, 0, 0);
    }
#pragma unroll
    for (int r = 0; r < 4; ++r) {
        red[w][kg * 4 + r][ 0 + lr] = acc0[r];
        red[w][kg * 4 + r][16 + lr] = acc1[r];
        red[w][kg * 4 + r][32 + lr] = acc2[r];
        red[w][kg * 4 + r][48 + lr] = acc3[r];
    }
    __syncthreads();
    int row = tid >> 4, col = (tid & 15) * 4;
    int I2 = i0 + row;
#pragma unroll
    for (int q = 0; q < 4; ++q) {
        int J = j0 + col + q;
        if (J < NP) {
            float v = 0.f;
            if (I2 < N_ && J < N_) {
                float r4 = ((red[0][row][col + q] + red[1][row][col + q]) +
                            (red[2][row][col + q] + red[3][row][col + q]));
                v = adj[I2 * N_ + J] + 2.f * r4;
            }
            S16[I2 * NP + J] = (_Float16)v;
        }
    }
}

// ---------------- K2: X16[n][bt][c] = f16(relu(inputs @ w_lt^T + b_lt)) ------
__global__ void k_lintrans(const float* __restrict__ in,
                           const float* __restrict__ w,    // (16,3)
                           const float* __restrict__ bias, // (16)
                           _Float16* __restrict__ X16) {
    int idx4 = (blockIdx.x * 256 + threadIdx.x) * 4;
    if (idx4 >= N_ * M_) return;
    int n = idx4 >> 12;
    int r = idx4 & 4095;
    int bt = r >> 4, c0 = r & 15;
    int tok = bt * N_ + n;
    float f0 = in[tok * 3 + 0];
    float f1 = in[tok * 3 + 1];
    float f2 = in[tok * 3 + 2];
    f16x4 o;
    o[0] = (_Float16)fmaxf(bias[c0+0] + f0*w[(c0+0)*3+0] + f1*w[(c0+0)*3+1] + f2*w[(c0+0)*3+2], 0.f);
    o[1] = (_Float16)fmaxf(bias[c0+1] + f0*w[(c0+1)*3+0] + f1*w[(c0+1)*3+1] + f2*w[(c0+1)*3+2], 0.f);
    o[2] = (_Float16)fmaxf(bias[c0+2] + f0*w[(c0+2)*3+0] + f1*w[(c0+2)*3+1] + f2*w[(c0+2)*3+2], 0.f);
    o[3] = (_Float16)fmaxf(bias[c0+3] + f0*w[(c0+3)*3+0] + f1*w[(c0+3)*3+1] + f2*w[(c0+3)*3+2], 0.f);
    *(f16x4*)&X16[idx4] = o;
}

// ---------------- K3: lfs16 = f16(S @ X) — f16 MFMA, in-block split-K --------
__global__ __launch_bounds__(256) void k_gconv(const _Float16* __restrict__ S16,
                                               const _Float16* __restrict__ X16,
                                               _Float16* __restrict__ lfs16) {
    __shared__ __align__(16) float red[4][16][68];
    int m0 = blockIdx.x * 64;
    int i0 = blockIdx.y * 16;
    int tid = threadIdx.x;
    int w = tid >> 6, l = tid & 63;
    int lr = l & 15, kg = l >> 4;

    int c0 = w * 5;
    int nc = (w == 3) ? 6 : 5;    // 21 chunks of K=16 total (336 = NP)

    f32x4 acc0 = {0.f,0.f,0.f,0.f}, acc1 = acc0, acc2 = acc0, acc3 = acc0;
    const size_t arow = (size_t)(i0 + lr) * NP;
    for (int cc = 0; cc < nc; ++cc) {
        int kb = (c0 + cc) * 16 + kg * 4;
        f16x4 af = *(const f16x4*)&S16[arow + kb];   // pads are zeroed
        f16x4 b0, b1, b2, b3;
#pragma unroll
        for (int j = 0; j < 4; ++j) {
            int k = kb + j;
            _Float16 x0 = (_Float16)0.f, x1 = x0, x2 = x0, x3 = x0;
            if (k < N_) {
                const _Float16* xr = X16 + (size_t)k * M_ + m0;
                x0 = xr[lr]; x1 = xr[16 + lr]; x2 = xr[32 + lr]; x3 = xr[48 + lr];
            }
            b0[j] = x0; b1[j] = x1; b2[j] = x2; b3[j] = x3;
        }
        acc0 = MFMA16(af, b0, acc0, 0, 0, 0);
        acc1 = MFMA16(af, b1, acc1, 0, 0, 0);
        acc2 = MFMA16(af, b2, acc2, 0, 0, 0);
        acc3 = MFMA16(af, b3, acc3, 0, 0, 0);
    }
#pragma unroll
    for (int r = 0; r < 4; ++r) {
        red[w][kg * 4 + r][ 0 + lr] = acc0[r];
        red[w][kg * 4 + r][16 + lr] = acc1[r];
        red[w][kg * 4 + r][32 + lr] = acc2[r];
        red[w][kg * 4 + r][48 + lr] = acc3[r];
    }
    __syncthreads();
    int row = tid >> 4, col = (tid & 15) * 4;
    if (i0 + row < N_) {
        float4 p0 = *(const float4*)&red[0][row][col];
        float4 p1 = *(const float4*)&red[1][row][col];
        float4 p2 = *(const float4*)&red[2][row][col];
        float4 p3 = *(const float4*)&red[3][row][col];
        f16x4 o;
        o[0] = (_Float16)((p0.x + p1.x) + (p2.x + p3.x));
        o[1] = (_Float16)((p0.y + p1.y) + (p2.y + p3.y));
        o[2] = (_Float16)((p0.z + p1.z) + (p2.z + p3.z));
        o[3] = (_Float16)((p0.w + p1.w) + (p2.w + p3.w));
        *(f16x4*)&lfs16[(size_t)(i0 + row) * M_ + m0 + col] = o;
    }
}

// ---------------- K4: MFMA attention — per-tt fused, low register pressure ---
__global__ __launch_bounds__(256) void k_attn(
    const _Float16* __restrict__ lfs16, const float* __restrict__ in,
    const float* __restrict__ wlt, const float* __restrict__ blt,
    const float* __restrict__ wq, const float* __restrict__ bq,
    const float* __restrict__ wk, const float* __restrict__ bk,
    const float* __restrict__ wv, const float* __restrict__ bv,
    const float* __restrict__ wls, const float* __restrict__ bls,
    _Float16* __restrict__ ypre16, float* __restrict__ part) {
    __shared__ __align__(16) float Rs[NH][T_][20];
    __shared__ float lnp[NH][2];
    int bn = blockIdx.x;
    int b = bn / N_, n = bn % N_;
    int tid = threadIdx.x;
    int h = tid >> 6;
    int l = tid & 63;
    int lr = l & 15, kg = l >> 4;

    // direct fragment loads: contiguous 512B per q across the wave
    const _Float16* Lsrc = lfs16 + (size_t)n * M_ + b * (T_ * DH);
    f16x4 lff[4];
#pragma unroll
    for (int q = 0; q < 4; ++q)
        lff[q] = *(const f16x4*)&Lsrc[(lr + 16 * q) * DH + kg * 4];

    f16x4 wqf, wkf, wvf, wlf;
    {
        int base = h * 16 + lr;
#pragma unroll
        for (int j = 0; j < 4; ++j) {
            wqf[j] = (_Float16)wq[(kg * 4 + j) * DD + base];
            wkf[j] = (_Float16)wk[(kg * 4 + j) * DD + base];
            wvf[j] = (_Float16)wv[(kg * 4 + j) * DD + base];
        }
        const float4 w4 = *(const float4*)&wls[lr * DD + h * 16 + kg * 4];
        wlf[0] = (_Float16)w4.x; wlf[1] = (_Float16)w4.y; wlf[2] = (_Float16)w4.z; wlf[3] = (_Float16)w4.w;
    }
    f32x4 zero = {0.f, 0.f, 0.f, 0.f};

    // QKV projections
    f16x4 qtf[4], ktf[4], vvf[4];
    {
        float bqr[4], bkr[4];
#pragma unroll
        for (int r = 0; r < 4; ++r) { bqr[r] = bq[h * 16 + kg * 4 + r]; bkr[r] = bk[h * 16 + kg * 4 + r]; }
        float bvc = bv[h * 16 + lr];
#pragma unroll
        for (int q = 0; q < 4; ++q) {
            f32x4 qa = MFMA16(wqf, lff[q], zero, 0, 0, 0);
            f32x4 ka = MFMA16(wkf, lff[q], zero, 0, 0, 0);
            f32x4 va = MFMA16(lff[q], wvf, zero, 0, 0, 0);
#pragma unroll
            for (int r = 0; r < 4; ++r) {
                qtf[q][r] = (_Float16)(fmaxf(qa[r] + bqr[r], 0.f) * 0.25f);
                ktf[q][r] = (_Float16)fmaxf(ka[r] + bkr[r], 0.f);
                vvf[q][r] = (_Float16)fmaxf(va[r] + bvc, 0.f);
            }
        }
    }

    // per-tt: scores -> cross-lane softmax -> mask -> PV -> proj -> stage
#pragma unroll
    for (int tt = 0; tt < 4; ++tt) {
        f32x4 stc[4];
#pragma unroll
        for (int ss = 0; ss < 4; ++ss)
            stc[ss] = MFMA16(ktf[ss], qtf[tt], zero, 0, 0, 0);
        int t = tt * 16 + lr;
        float m = -1e30f;
#pragma unroll
        for (int ss = 0; ss < 4; ++ss)
#pragma unroll
            for (int r = 0; r < 4; ++r) m = fmaxf(m, stc[ss][r]);
        m = fmaxf(m, __shfl_xor(m, 16));
        m = fmaxf(m, __shfl_xor(m, 32));
        float e[4][4];
        float sum = 0.f;
#pragma unroll
        for (int ss = 0; ss < 4; ++ss)
#pragma unroll
            for (int r = 0; r < 4; ++r) { float ev = __expf(stc[ss][r] - m); e[ss][r] = ev; sum += ev; }
        sum += __shfl_xor(sum, 16);
        sum += __shfl_xor(sum, 32);
        float inv = 1.f / sum;
        f16x4 pc[4];
#pragma unroll
        for (int ss = 0; ss < 4; ++ss)
#pragma unroll
            for (int r = 0; r < 4; ++r) {
                int s = ss * 16 + kg * 4 + r;
                pc[ss][r] = (s <= t) ? (_Float16)(e[ss][r] * inv) : (_Float16)0.f;
            }
        f32x4 acc = zero;
#pragma unroll
        for (int ss = 0; ss < 4; ++ss)
            acc = MFMA16(vvf[ss], pc[ss], acc, 0, 0, 0);
        f16x4 rt;
#pragma unroll
        for (int r = 0; r < 4; ++r) rt[r] = (_Float16)fmaxf(acc[r], 0.f);
        f32x4 rp = MFMA16(wlf, rt, zero, 0, 0, 0);
        float4 o4; o4.x = rp[0]; o4.y = rp[1]; o4.z = rp[2]; o4.w = rp[3];
        *(float4*)&Rs[h][t][kg * 4] = o4;
    }
    __syncthreads();

    // epilogue: cross-head sum + bls + relu + residual + LN partials
    {
        int t = tid >> 2, o0 = (tid & 3) * 4;
        float4 r0 = *(const float4*)&Rs[0][t][o0];
        float4 r1 = *(const float4*)&Rs[1][t][o0];
        float4 r2 = *(const float4*)&Rs[2][t][o0];
        float4 r3 = *(const float4*)&Rs[3][t][o0];
        int tok = ((b * T_ + t) * N_ + n) * 3;
        float f0 = in[tok], f1 = in[tok + 1], f2 = in[tok + 2];
        float xv[4];
#pragma unroll
        for (int i = 0; i < 4; ++i) {
            int c = o0 + i;
            xv[i] = fmaxf(blt[c] + f0 * wlt[c * 3 + 0] + f1 * wlt[c * 3 + 1] + f2 * wlt[c * 3 + 2], 0.f);
        }
        float y0 = xv[0] + fmaxf(r0.x + r1.x + r2.x + r3.x + bls[o0 + 0], 0.f);
        float y1 = xv[1] + fmaxf(r0.y + r1.y + r2.y + r3.y + bls[o0 + 1], 0.f);
        float y2 = xv[2] + fmaxf(r0.z + r1.z + r2.z + r3.z + bls[o0 + 2], 0.f);
        float y3 = xv[3] + fmaxf(r0.w + r1.w + r2.w + r3.w + bls[o0 + 3], 0.f);
        f16x4 yv16;
        yv16[0] = (_Float16)y0; yv16[1] = (_Float16)y1;
        yv16[2] = (_Float16)y2; yv16[3] = (_Float16)y3;
        *(f16x4*)&ypre16[(size_t)b * 332800 + (size_t)n * 1024 + t * DH + o0] = yv16;
        float ls = (y0 + y1) + (y2 + y3);
        float lq = (y0 * y0 + y1 * y1) + (y2 * y2 + y3 * y3);
#pragma unroll
        for (int off = 32; off > 0; off >>= 1) { ls += __shfl_down(ls, off); lq += __shfl_down(lq, off); }
        if (l == 0) { lnp[h][0] = ls; lnp[h][1] = lq; }
    }
    __syncthreads();
    if (tid == 0) {
        part[bn * 2]     = (lnp[0][0] + lnp[1][0]) + (lnp[2][0] + lnp[3][0]);
        part[bn * 2 + 1] = (lnp[0][1] + lnp[1][1]) + (lnp[2][1] + lnp[3][1]);
    }
}

// ---------------- K5: folded stats + normalize + gamma/beta ------------------
// 1300 blocks; block = one (b,n): reduces its batch's 650 partials, then
// normalizes 1024 contiguous ypre16 elements.
__global__ __launch_bounds__(256) void k_lnapply(const _Float16* __restrict__ y16,
                                                 const float* __restrict__ part,
                                                 const float* __restrict__ gamma,
                                                 const float* __restrict__ beta,
                                                 float* __restrict__ out) {
    __shared__ float ssum[256], ssq[256];
    int blk = blockIdx.x, tid = threadIdx.x;
    int b = blk / N_, n = blk % N_;
    float s = 0.f, q = 0.f;
    for (int i = tid; i < N_; i += 256) {
        s += part[(b * N_ + i) * 2];
        q += part[(b * N_ + i) * 2 + 1];
    }
    ssum[tid] = s; ssq[tid] = q;
    __syncthreads();
    for (int st = 128; st > 0; st >>= 1) {
        if (tid < st) { ssum[tid] += ssum[tid + st]; ssq[tid] += ssq[tid + st]; }
        __syncthreads();
    }
    float mu = ssum[0] / 332800.f;
    float var = ssq[0] / 332800.f - mu * mu;
    float rs = rsqrtf(var + 1e-5f);

    int rr = tid * 4;
    int t = rr >> 4, c0 = rr & 15;
    f16x4 yv = *(const f16x4*)&y16[(size_t)blk * 1024 + rr];
    int g0 = ((c0 + 0) * T_ + t) * N_ + n;
    int g1 = ((c0 + 1) * T_ + t) * N_ + n;
    int g2 = ((c0 + 2) * T_ + t) * N_ + n;
    int g3 = ((c0 + 3) * T_ + t) * N_ + n;
    float4 o;
    o.x = ((float)yv[0] - mu) * rs * gamma[g0] + beta[g0];
    o.y = ((float)yv[1] - mu) * rs * gamma[g1] + beta[g1];
    o.z = ((float)yv[2] - mu) * rs * gamma[g2] + beta[g2];
    o.w = ((float)yv[3] - mu) * rs * gamma[g3] + beta[g3];
    *(float4*)&out[(((size_t)(b * T_ + t) * N_) + n) * DH + c0] = o;
}

extern "C" void kernel_launch(void* const* d_in, const int* in_sizes, int n_in,
                              void* d_out, int out_size, void* d_ws, size_t ws_size,
                              hipStream_t stream) {
    const float* in   = (const float*)d_in[0];
    const float* adj  = (const float*)d_in[1];
    const float* w_lt = (const float*)d_in[2];
    const float* b_lt = (const float*)d_in[3];
    const float* wq   = (const float*)d_in[4];
    const float* bq   = (const float*)d_in[5];
    const float* wk   = (const float*)d_in[6];
    const float* bk   = (const float*)d_in[7];
    const float* wv   = (const float*)d_in[8];
    const float* bv   = (const float*)d_in[9];
    const float* wls  = (const float*)d_in[10];
    const float* bls  = (const float*)d_in[11];
    const float* gam  = (const float*)d_in[12];
    const float* bet  = (const float*)d_in[13];
    float* out = (float*)d_out;

    float* ws = (float*)d_ws;
    _Float16* S16 = (_Float16*)ws;                        // NP*NP f16
    _Float16* X16 = (_Float16*)(ws + 56576);              // 1,331,200 f16
    _Float16* lfs16 = (_Float16*)(ws + 56576 + 665600);   // 1,331,200 f16
    _Float16* ypre16 = (_Float16*)(ws + 56576 + 665600 + 665600);  // 1,331,200 f16
    float* part = ws + 56576 + 665600 + 665600 + 665600;  // 2600

    k_support<<<dim3(6, 21), 256, 0, stream>>>(adj, S16);
    k_lintrans<<<(N_ * M_) / 1024, 256, 0, stream>>>(in, w_lt, b_lt, X16);
    k_gconv<<<dim3(64, 21), 256, 0, stream>>>(S16, X16, lfs16);
    k_attn<<<B_ * N_, 256, 0, stream>>>(lfs16, in, w_lt, b_lt, wq, bq, wk, bk, wv, bv, wls, bls, ypre16, part);
    k_lnapply<<<B_ * N_, 256, 0, stream>>>(ypre16, part, gam, bet, out);
}

// Round 14
// 61.120 us; speedup vs baseline: 3.2056x; 1.1742x over previous
//
#include <hip/hip_runtime.h>
#include <hip/hip_bf16.h>

#define B_ 4
#define T_ 64
#define N_ 325
#define NP 336                  // padded graph dim for MFMA
#define F_ 3
#define DH 16
#define DD 64
#define NH 4
#define BT_ 256                 // B*T
#define M_ 4096                 // BT*DH  (GEMM N-dim)

using f16x4 = __attribute__((ext_vector_type(4))) _Float16;
using f32x4 = __attribute__((ext_vector_type(4))) float;
#define MFMA16 __builtin_amdgcn_mfma_f32_16x16x16f16

// ---------------- K1: fused {support-MFMA | lintrans} by block range ---------
// blocks [0,126): S16 = f16(adj + 2*adj@adj), 64j x 16i tiles, split-K
// blocks [126,1426): X16 = f16(relu(inputs @ w_lt^T + b_lt))
__global__ __launch_bounds__(256) void k_prep(const float* __restrict__ adj,
                                              const float* __restrict__ in,
                                              const float* __restrict__ w,
                                              const float* __restrict__ bias,
                                              _Float16* __restrict__ S16,
                                              _Float16* __restrict__ X16) {
    int tid = threadIdx.x;
    if (blockIdx.x < 126) {
        __shared__ __align__(16) float red[4][16][68];
        int sb = blockIdx.x;
        int j0 = (sb % 6) * 64;
        int i0 = (sb / 6) * 16;
        int w4 = tid >> 6, l = tid & 63;
        int lr = l & 15, kg = l >> 4;
        int c0 = w4 * 5;
        int nc = (w4 == 3) ? 6 : 5;    // 21 K-chunks of 16 over NP=336

        f32x4 acc0 = {0.f,0.f,0.f,0.f}, acc1 = acc0, acc2 = acc0, acc3 = acc0;
        int I = i0 + lr;
        for (int cc = 0; cc < nc; ++cc) {
            int kb = (c0 + cc) * 16 + kg * 4;
            f16x4 af, b0, b1, b2, b3;
#pragma unroll
            for (int j = 0; j < 4; ++j) {
                int k = kb + j;
                af[j] = (I < N_ && k < N_) ? (_Float16)adj[I * N_ + k] : (_Float16)0.f;
                _Float16 x0 = (_Float16)0.f, x1 = x0, x2 = x0, x3 = x0;
                if (k < N_) {
                    const float* ar = adj + (size_t)k * N_;
                    int m0 = j0 + lr;
                    if (m0 < N_)      x0 = (_Float16)ar[m0];
                    if (m0 + 16 < N_) x1 = (_Float16)ar[m0 + 16];
                    if (m0 + 32 < N_) x2 = (_Float16)ar[m0 + 32];
                    if (m0 + 48 < N_) x3 = (_Float16)ar[m0 + 48];
                }
                b0[j] = x0; b1[j] = x1; b2[j] = x2; b3[j] = x3;
            }
            acc0 = MFMA16(af, b0, acc0, 0, 0, 0);
            acc1 = MFMA16(af, b1, acc1, 0, 0, 0);
            acc2 = MFMA16(af, b2, acc2, 0, 0, 0);
            acc3 = MFMA16(af, b3, acc3, 0, 0, 0);
        }
#pragma unroll
        for (int r = 0; r < 4; ++r) {
            red[w4][kg * 4 + r][ 0 + lr] = acc0[r];
            red[w4][kg * 4 + r][16 + lr] = acc1[r];
            red[w4][kg * 4 + r][32 + lr] = acc2[r];
            red[w4][kg * 4 + r][48 + lr] = acc3[r];
        }
        __syncthreads();
        int row = tid >> 4, col = (tid & 15) * 4;
        int I2 = i0 + row;
#pragma unroll
        for (int q = 0; q < 4; ++q) {
            int J = j0 + col + q;
            if (J < NP) {
                float v = 0.f;
                if (I2 < N_ && J < N_) {
                    float r4 = ((red[0][row][col + q] + red[1][row][col + q]) +
                                (red[2][row][col + q] + red[3][row][col + q]));
                    v = adj[I2 * N_ + J] + 2.f * r4;
                }
                S16[I2 * NP + J] = (_Float16)v;
            }
        }
    } else {
        int idx4 = ((blockIdx.x - 126) * 256 + tid) * 4;
        if (idx4 >= N_ * M_) return;
        int n = idx4 >> 12;
        int r = idx4 & 4095;
        int bt = r >> 4, c0 = r & 15;
        int tok = bt * N_ + n;
        float f0 = in[tok * 3 + 0];
        float f1 = in[tok * 3 + 1];
        float f2 = in[tok * 3 + 2];
        f16x4 o;
        o[0] = (_Float16)fmaxf(bias[c0+0] + f0*w[(c0+0)*3+0] + f1*w[(c0+0)*3+1] + f2*w[(c0+0)*3+2], 0.f);
        o[1] = (_Float16)fmaxf(bias[c0+1] + f0*w[(c0+1)*3+0] + f1*w[(c0+1)*3+1] + f2*w[(c0+1)*3+2], 0.f);
        o[2] = (_Float16)fmaxf(bias[c0+2] + f0*w[(c0+2)*3+0] + f1*w[(c0+2)*3+1] + f2*w[(c0+2)*3+2], 0.f);
        o[3] = (_Float16)fmaxf(bias[c0+3] + f0*w[(c0+3)*3+0] + f1*w[(c0+3)*3+1] + f2*w[(c0+3)*3+2], 0.f);
        *(f16x4*)&X16[idx4] = o;
    }
}

// ---------------- K3: lfs16 = f16(S @ X) — f16 MFMA, in-block split-K --------
__global__ __launch_bounds__(256) void k_gconv(const _Float16* __restrict__ S16,
                                               const _Float16* __restrict__ X16,
                                               _Float16* __restrict__ lfs16) {
    __shared__ __align__(16) float red[4][16][68];
    int m0 = blockIdx.x * 64;
    int i0 = blockIdx.y * 16;
    int tid = threadIdx.x;
    int w = tid >> 6, l = tid & 63;
    int lr = l & 15, kg = l >> 4;

    int c0 = w * 5;
    int nc = (w == 3) ? 6 : 5;    // 21 chunks of K=16 total (336 = NP)

    f32x4 acc0 = {0.f,0.f,0.f,0.f}, acc1 = acc0, acc2 = acc0, acc3 = acc0;
    const size_t arow = (size_t)(i0 + lr) * NP;
    for (int cc = 0; cc < nc; ++cc) {
        int kb = (c0 + cc) * 16 + kg * 4;
        f16x4 af = *(const f16x4*)&S16[arow + kb];   // pads are zeroed
        f16x4 b0, b1, b2, b3;
#pragma unroll
        for (int j = 0; j < 4; ++j) {
            int k = kb + j;
            _Float16 x0 = (_Float16)0.f, x1 = x0, x2 = x0, x3 = x0;
            if (k < N_) {
                const _Float16* xr = X16 + (size_t)k * M_ + m0;
                x0 = xr[lr]; x1 = xr[16 + lr]; x2 = xr[32 + lr]; x3 = xr[48 + lr];
            }
            b0[j] = x0; b1[j] = x1; b2[j] = x2; b3[j] = x3;
        }
        acc0 = MFMA16(af, b0, acc0, 0, 0, 0);
        acc1 = MFMA16(af, b1, acc1, 0, 0, 0);
        acc2 = MFMA16(af, b2, acc2, 0, 0, 0);
        acc3 = MFMA16(af, b3, acc3, 0, 0, 0);
    }
#pragma unroll
    for (int r = 0; r < 4; ++r) {
        red[w][kg * 4 + r][ 0 + lr] = acc0[r];
        red[w][kg * 4 + r][16 + lr] = acc1[r];
        red[w][kg * 4 + r][32 + lr] = acc2[r];
        red[w][kg * 4 + r][48 + lr] = acc3[r];
    }
    __syncthreads();
    int row = tid >> 4, col = (tid & 15) * 4;
    if (i0 + row < N_) {
        float4 p0 = *(const float4*)&red[0][row][col];
        float4 p1 = *(const float4*)&red[1][row][col];
        float4 p2 = *(const float4*)&red[2][row][col];
        float4 p3 = *(const float4*)&red[3][row][col];
        f16x4 o;
        o[0] = (_Float16)((p0.x + p1.x) + (p2.x + p3.x));
        o[1] = (_Float16)((p0.y + p1.y) + (p2.y + p3.y));
        o[2] = (_Float16)((p0.z + p1.z) + (p2.z + p3.z));
        o[3] = (_Float16)((p0.w + p1.w) + (p2.w + p3.w));
        *(f16x4*)&lfs16[(size_t)(i0 + row) * M_ + m0 + col] = o;
    }
}

// ---------------- K4: MFMA attention — per-tt fused --------------------------
__global__ __launch_bounds__(256) void k_attn(
    const _Float16* __restrict__ lfs16, const float* __restrict__ in,
    const float* __restrict__ wlt, const float* __restrict__ blt,
    const float* __restrict__ wq, const float* __restrict__ bq,
    const float* __restrict__ wk, const float* __restrict__ bk,
    const float* __restrict__ wv, const float* __restrict__ bv,
    const float* __restrict__ wls, const float* __restrict__ bls,
    _Float16* __restrict__ ypre16, float* __restrict__ part) {
    __shared__ __align__(16) float Rs[NH][T_][20];
    __shared__ float lnp[NH][2];
    int bn = blockIdx.x;
    int b = bn / N_, n = bn % N_;
    int tid = threadIdx.x;
    int h = tid >> 6;
    int l = tid & 63;
    int lr = l & 15, kg = l >> 4;

    const _Float16* Lsrc = lfs16 + (size_t)n * M_ + b * (T_ * DH);
    f16x4 lff[4];
#pragma unroll
    for (int q = 0; q < 4; ++q)
        lff[q] = *(const f16x4*)&Lsrc[(lr + 16 * q) * DH + kg * 4];

    f16x4 wqf, wkf, wvf, wlf;
    {
        int base = h * 16 + lr;
#pragma unroll
        for (int j = 0; j < 4; ++j) {
            wqf[j] = (_Float16)wq[(kg * 4 + j) * DD + base];
            wkf[j] = (_Float16)wk[(kg * 4 + j) * DD + base];
            wvf[j] = (_Float16)wv[(kg * 4 + j) * DD + base];
        }
        const float4 w4 = *(const float4*)&wls[lr * DD + h * 16 + kg * 4];
        wlf[0] = (_Float16)w4.x; wlf[1] = (_Float16)w4.y; wlf[2] = (_Float16)w4.z; wlf[3] = (_Float16)w4.w;
    }
    f32x4 zero = {0.f, 0.f, 0.f, 0.f};

    f16x4 qtf[4], ktf[4], vvf[4];
    {
        float bqr[4], bkr[4];
#pragma unroll
        for (int r = 0; r < 4; ++r) { bqr[r] = bq[h * 16 + kg * 4 + r]; bkr[r] = bk[h * 16 + kg * 4 + r]; }
        float bvc = bv[h * 16 + lr];
#pragma unroll
        for (int q = 0; q < 4; ++q) {
            f32x4 qa = MFMA16(wqf, lff[q], zero, 0, 0, 0);
            f32x4 ka = MFMA16(wkf, lff[q], zero, 0, 0, 0);
            f32x4 va = MFMA16(lff[q], wvf, zero, 0, 0, 0);
#pragma unroll
            for (int r = 0; r < 4; ++r) {
                qtf[q][r] = (_Float16)(fmaxf(qa[r] + bqr[r], 0.f) * 0.25f);
                ktf[q][r] = (_Float16)fmaxf(ka[r] + bkr[r], 0.f);
                vvf[q][r] = (_Float16)fmaxf(va[r] + bvc, 0.f);
            }
        }
    }

#pragma unroll
    for (int tt = 0; tt < 4; ++tt) {
        f32x4 stc[4];
#pragma unroll
        for (int ss = 0; ss < 4; ++ss)
            stc[ss] = MFMA16(ktf[ss], qtf[tt], zero, 0, 0, 0);
        int t = tt * 16 + lr;
        float m = -1e30f;
#pragma unroll
        for (int ss = 0; ss < 4; ++ss)
#pragma unroll
            for (int r = 0; r < 4; ++r) m = fmaxf(m, stc[ss][r]);
        m = fmaxf(m, __shfl_xor(m, 16));
        m = fmaxf(m, __shfl_xor(m, 32));
        float e[4][4];
        float sum = 0.f;
#pragma unroll
        for (int ss = 0; ss < 4; ++ss)
#pragma unroll
            for (int r = 0; r < 4; ++r) { float ev = __expf(stc[ss][r] - m); e[ss][r] = ev; sum += ev; }
        sum += __shfl_xor(sum, 16);
        sum += __shfl_xor(sum, 32);
        float inv = 1.f / sum;
        f16x4 pc[4];
#pragma unroll
        for (int ss = 0; ss < 4; ++ss)
#pragma unroll
            for (int r = 0; r < 4; ++r) {
                int s = ss * 16 + kg * 4 + r;
                pc[ss][r] = (s <= t) ? (_Float16)(e[ss][r] * inv) : (_Float16)0.f;
            }
        f32x4 acc = zero;
#pragma unroll
        for (int ss = 0; ss < 4; ++ss)
            acc = MFMA16(vvf[ss], pc[ss], acc, 0, 0, 0);
        f16x4 rt;
#pragma unroll
        for (int r = 0; r < 4; ++r) rt[r] = (_Float16)fmaxf(acc[r], 0.f);
        f32x4 rp = MFMA16(wlf, rt, zero, 0, 0, 0);
        float4 o4; o4.x = rp[0]; o4.y = rp[1]; o4.z = rp[2]; o4.w = rp[3];
        *(float4*)&Rs[h][t][kg * 4] = o4;
    }
    __syncthreads();

    {
        int t = tid >> 2, o0 = (tid & 3) * 4;
        float4 r0 = *(const float4*)&Rs[0][t][o0];
        float4 r1 = *(const float4*)&Rs[1][t][o0];
        float4 r2 = *(const float4*)&Rs[2][t][o0];
        float4 r3 = *(const float4*)&Rs[3][t][o0];
        int tok = ((b * T_ + t) * N_ + n) * 3;
        float f0 = in[tok], f1 = in[tok + 1], f2 = in[tok + 2];
        float xv[4];
#pragma unroll
        for (int i = 0; i < 4; ++i) {
            int c = o0 + i;
            xv[i] = fmaxf(blt[c] + f0 * wlt[c * 3 + 0] + f1 * wlt[c * 3 + 1] + f2 * wlt[c * 3 + 2], 0.f);
        }
        float y0 = xv[0] + fmaxf(r0.x + r1.x + r2.x + r3.x + bls[o0 + 0], 0.f);
        float y1 = xv[1] + fmaxf(r0.y + r1.y + r2.y + r3.y + bls[o0 + 1], 0.f);
        float y2 = xv[2] + fmaxf(r0.z + r1.z + r2.z + r3.z + bls[o0 + 2], 0.f);
        float y3 = xv[3] + fmaxf(r0.w + r1.w + r2.w + r3.w + bls[o0 + 3], 0.f);
        f16x4 yv16;
        yv16[0] = (_Float16)y0; yv16[1] = (_Float16)y1;
        yv16[2] = (_Float16)y2; yv16[3] = (_Float16)y3;
        *(f16x4*)&ypre16[(size_t)b * 332800 + (size_t)n * 1024 + t * DH + o0] = yv16;
        float ls = (y0 + y1) + (y2 + y3);
        float lq = (y0 * y0 + y1 * y1) + (y2 * y2 + y3 * y3);
#pragma unroll
        for (int off = 32; off > 0; off >>= 1) { ls += __shfl_down(ls, off); lq += __shfl_down(lq, off); }
        if (l == 0) { lnp[h][0] = ls; lnp[h][1] = lq; }
    }
    __syncthreads();
    if (tid == 0) {
        part[bn * 2]     = (lnp[0][0] + lnp[1][0]) + (lnp[2][0] + lnp[3][0]);
        part[bn * 2 + 1] = (lnp[0][1] + lnp[1][1]) + (lnp[2][1] + lnp[3][1]);
    }
}

// ---------------- K5: LN stats + normalize, block = (b,t) --------------------
// gamma/beta slices staged in LDS (coalesced); out written contiguous.
__global__ __launch_bounds__(256) void k_lnapply(const _Float16* __restrict__ y16,
                                                 const float* __restrict__ part,
                                                 const float* __restrict__ gamma,
                                                 const float* __restrict__ beta,
                                                 float* __restrict__ out) {
    __shared__ float gs[N_ * DH];   // 20.8 KB, layout [c][n]
    __shared__ float bs[N_ * DH];   // 20.8 KB
    __shared__ float ssum[256], ssq[256];
    int blk = blockIdx.x, tid = threadIdx.x;
    int b = blk >> 6, t = blk & 63;
    for (int i = tid; i < N_ * DH; i += 256) {      // i = c*325 + n: contiguous runs
        int c = i / N_, n = i - c * N_;
        size_t g = (size_t)(c * T_ + t) * N_ + n;
        gs[i] = gamma[g];
        bs[i] = beta[g];
    }
    float s = 0.f, q = 0.f;
    for (int i = tid; i < N_; i += 256) {
        s += part[(b * N_ + i) * 2];
        q += part[(b * N_ + i) * 2 + 1];
    }
    ssum[tid] = s; ssq[tid] = q;
    __syncthreads();
    for (int st = 128; st > 0; st >>= 1) {
        if (tid < st) { ssum[tid] += ssum[tid + st]; ssq[tid] += ssq[tid + st]; }
        __syncthreads();
    }
    float mu = ssum[0] / 332800.f;
    float rs = rsqrtf(ssq[0] / 332800.f - mu * mu + 1e-5f);

    float* ob = out + (size_t)(b * T_ + t) * (N_ * DH);
    const _Float16* yb = y16 + (size_t)b * 332800 + t * DH;
    for (int e = tid; e < N_ * DH; e += 256) {      // e = n*16+c: out contiguous
        int n = e >> 4, c = e & 15;
        float yv = (float)yb[(size_t)n * 1024 + c];
        ob[e] = (yv - mu) * rs * gs[c * N_ + n] + bs[c * N_ + n];
    }
}

extern "C" void kernel_launch(void* const* d_in, const int* in_sizes, int n_in,
                              void* d_out, int out_size, void* d_ws, size_t ws_size,
                              hipStream_t stream) {
    const float* in   = (const float*)d_in[0];
    const float* adj  = (const float*)d_in[1];
    const float* w_lt = (const float*)d_in[2];
    const float* b_lt = (const float*)d_in[3];
    const float* wq   = (const float*)d_in[4];
    const float* bq   = (const float*)d_in[5];
    const float* wk   = (const float*)d_in[6];
    const float* bk   = (const float*)d_in[7];
    const float* wv   = (const float*)d_in[8];
    const float* bv   = (const float*)d_in[9];
    const float* wls  = (const float*)d_in[10];
    const float* bls  = (const float*)d_in[11];
    const float* gam  = (const float*)d_in[12];
    const float* bet  = (const float*)d_in[13];
    float* out = (float*)d_out;

    float* ws = (float*)d_ws;
    _Float16* S16 = (_Float16*)ws;                        // NP*NP f16
    _Float16* X16 = (_Float16*)(ws + 56576);              // 1,331,200 f16
    _Float16* lfs16 = (_Float16*)(ws + 56576 + 665600);   // 1,331,200 f16
    _Float16* ypre16 = (_Float16*)(ws + 56576 + 665600 + 665600);  // 1,331,200 f16
    float* part = ws + 56576 + 665600 + 665600 + 665600;  // 2600

    k_prep<<<126 + 1300, 256, 0, stream>>>(adj, in, w_lt, b_lt, S16, X16);
    k_gconv<<<dim3(64, 21), 256, 0, stream>>>(S16, X16, lfs16);
    k_attn<<<B_ * N_, 256, 0, stream>>>(lfs16, in, w_lt, b_lt, wq, bq, wk, bk, wv, bv, wls, bls, ypre16, part);
    k_lnapply<<<B_ * T_, 256, 0, stream>>>(ypre16, part, gam, bet, out);
}